// Round 16
// baseline (860.372 us; speedup 1.0000x reference)
//
#include <hip/hip_runtime.h>
#include <math.h>

#define N_NODES 100000
#define N_EDGES 1600000
#define EN_TOT  (N_EDGES + N_NODES)
#define BATCH   16
#define EDGE_DIM 16
#define NEG_SLOPE 0.2f
#define NB_SCAN 391   // ceil(N_NODES/256)
#define LOG2E 1.44269504f

typedef float v2f __attribute__((ext_vector_type(2)));

__device__ __forceinline__ int rfl(int v) { return __builtin_amdgcn_readfirstlane(v); }

__device__ __forceinline__ v2f fma2(v2f a, v2f b, v2f c) {
#if __has_builtin(__builtin_elementwise_fma)
    return __builtin_elementwise_fma(a, b, c);
#else
    v2f r; r.x = fmaf(a.x, b.x, c.x); r.y = fmaf(a.y, b.y, c.y); return r;
#endif
}
__device__ __forceinline__ v2f max2(v2f a, v2f b) {
#if __has_builtin(__builtin_elementwise_max)
    return __builtin_elementwise_max(a, b);
#else
    v2f r; r.x = fmaxf(a.x, b.x); r.y = fmaxf(a.y, b.y); return r;
#endif
}

// DPP cross-lane add (VALU pipe, no DS round-trip / lgkmcnt stall).
template<int CTRL>
__device__ __forceinline__ float dpp_add(float p) {
    int t = __builtin_amdgcn_update_dpp(0, __float_as_int(p), CTRL, 0xF, 0xF, true);
    return p + __int_as_float(t);
}
// reduce-add over each 16-lane group, result in ALL 16 lanes.
__device__ __forceinline__ float red16(float p) {
    p = dpp_add<0xB1>(p);    // quad_perm [1,0,3,2] : xor1
    p = dpp_add<0x4E>(p);    // quad_perm [2,3,0,1] : xor2
    p = dpp_add<0x141>(p);   // row_half_mirror     : xor4-equivalent
    p = dpp_add<0x140>(p);   // row_mirror          : xor8-equivalent
    return p;
}

// ---------------- utility ----------------
__global__ void zero_kernel(float* __restrict__ p, long long n) {
    long long i = (long long)blockIdx.x * blockDim.x + threadIdx.x;
    long long stride = (long long)gridDim.x * blockDim.x;
    for (; i < n; i += stride) p[i] = 0.0f;
}

// ---------------- CSR build ----------------
__global__ void count_deg(const int* __restrict__ dst, int* __restrict__ deg) {
    int e = blockIdx.x * 256 + threadIdx.x;
    if (e < N_EDGES) atomicAdd(&deg[dst[e]], 1);
}

__global__ __launch_bounds__(256) void scan1(const int* __restrict__ deg,
                                             int* __restrict__ incl, int* __restrict__ bsum) {
    __shared__ int s[256];
    int n = blockIdx.x * 256 + threadIdx.x;
    int v = (n < N_NODES) ? deg[n] + 1 : 0;
    s[threadIdx.x] = v;
    __syncthreads();
    for (int off = 1; off < 256; off <<= 1) {
        int t = (threadIdx.x >= off) ? s[threadIdx.x - off] : 0;
        __syncthreads();
        s[threadIdx.x] += t;
        __syncthreads();
    }
    if (n < N_NODES) incl[n] = s[threadIdx.x];
    if (threadIdx.x == 255) bsum[blockIdx.x] = s[255];
}

__global__ __launch_bounds__(512) void scan2(int* __restrict__ bsum) {
    __shared__ int s[512];
    int t = threadIdx.x;
    int v = (t < NB_SCAN) ? bsum[t] : 0;
    s[t] = v;
    __syncthreads();
    for (int off = 1; off < 512; off <<= 1) {
        int u = (t >= off) ? s[t - off] : 0;
        __syncthreads();
        s[t] += u;
        __syncthreads();
    }
    if (t < NB_SCAN) bsum[t] = s[t] - v;  // exclusive block prefix
}

__global__ void scan3(const int* __restrict__ incl, const int* __restrict__ deg,
                      const int* __restrict__ bsum, int* __restrict__ offs) {
    int n = blockIdx.x * 256 + threadIdx.x;
    if (n < N_NODES) offs[n] = incl[n] - (deg[n] + 1) + bsum[blockIdx.x];
    if (n == 0) offs[N_NODES] = EN_TOT;
}

// scatter edges into CSR slots (packed {src, eid}); self-loop in LAST slot of each row
__global__ void scatter(const int* __restrict__ src, const int* __restrict__ dst,
                        const int* __restrict__ offs, int* __restrict__ cursor,
                        int2* __restrict__ csr) {
    int e = blockIdx.x * 256 + threadIdx.x;
    if (e < N_EDGES) {
        int d = dst[e];
        int r = atomicAdd(&cursor[d], 1);
        csr[offs[d] + r] = make_int2(src[e], e);
    } else if (e < EN_TOT) {
        int n = e - N_EDGES;
        csr[offs[n + 1] - 1] = make_int2(n, N_EDGES + n);  // self-loop marker
    }
}

__global__ __launch_bounds__(256) void loopattr_csr(const int* __restrict__ offs,
                                                    const int2* __restrict__ csr,
                                                    const float* __restrict__ ea,
                                                    float* __restrict__ lattr) {
    int node = blockIdx.x * 4 + (threadIdx.x >> 6);
    if (node >= N_NODES) return;
    int lane = threadIdx.x & 63;
    int row = offs[node];
    int degn = offs[node + 1] - 1 - row;  // real edges only
    int k = lane & 15, grp = lane >> 4;
    float acc = 0.0f;
    for (int i = grp; i < degn; i += 4) {
        int eid = csr[row + i].y;
        acc += ea[(long long)eid * EDGE_DIM + k];
    }
    acc += __shfl_xor(acc, 16);
    acc += __shfl_xor(acc, 32);
    if (lane < 16) lattr[(long long)node * EDGE_DIM + k] = acc / fmaxf((float)degn, 1.0f);
}

// ---------------- dense transforms ----------------
// R10-proven structure; float4 LDS staging (ds_read_b128 broadcast).
// Scalar float acc[32] + tight kk loop (no ext-vector acc -> no R6 spill).
template<int K>
__global__ __launch_bounds__(256) void dual_linear(
    const float* __restrict__ in,
    const float* __restrict__ Wl, const float* __restrict__ bl,
    const float* __restrict__ Wr, const float* __restrict__ br,
    float* __restrict__ outl, float* __restrict__ outr, int N)
{
    constexpr int ROWS = 32;
    constexpr int K4 = K / 4;
    __shared__ float4 srow[ROWS][K4];
    int t = threadIdx.x;
    int base = blockIdx.x * ROWS;
    {
        const float4* in4 = (const float4*)in;
        for (int i = t; i < ROWS * K4; i += 256) {
            int r = i / K4, k = i - r * K4;
            int n = base + r;
            srow[r][k] = (n < N) ? in4[(size_t)n * K4 + k] : make_float4(0.f, 0.f, 0.f, 0.f);
        }
    }
    __syncthreads();
    const float* W  = (t < 128) ? Wl : Wr;
    const float* bb = (t < 128) ? bl : br;
    float* outp     = (t < 128) ? outl : outr;
    int j = t & 127;
    float bj = bb[j];
    float acc[ROWS];
#pragma unroll
    for (int r = 0; r < ROWS; ++r) acc[r] = bj;
    const float4* W4 = (const float4*)(W + (size_t)j * K);
    for (int kk = 0; kk < K4; ++kk) {
        float4 w = W4[kk];
#pragma unroll
        for (int r = 0; r < ROWS; ++r) {
            float4 a = srow[r][kk];   // wave-uniform -> ds_read_b128 broadcast
            acc[r] = fmaf(a.x, w.x, acc[r]);
            acc[r] = fmaf(a.y, w.y, acc[r]);
            acc[r] = fmaf(a.z, w.z, acc[r]);
            acc[r] = fmaf(a.w, w.w, acc[r]);
        }
    }
    for (int r = 0; r < ROWS; ++r) {
        int n = base + r;
        if (n < N) outp[(long long)n * 128 + j] = acc[r];
    }
}

// ---------------- fused GATv2 (depth-2 pipeline + csr-ahead-4, DPP reduce, pk body) ----
// 128-thread blocks, 2 nodes/block (less degree-straggler waste than 4).
// lane owns ADJACENT channels (2*lane, 2*lane+1), same head; one softmax state/lane;
// packed (VOP3P) elementwise chain; csr held 4 ahead in SGPRs; depth-2 attr/xl slots.
template<int DO_ELU>
__global__ __launch_bounds__(128) void gat_fused(
    const int* __restrict__ offs, const int2* __restrict__ csr,
    const float* __restrict__ ea, const float* __restrict__ lattr,
    const float* __restrict__ We, const float* __restrict__ att,
    const v2f* __restrict__ xl2, const v2f* __restrict__ xr2,
    const float* __restrict__ bias, float* __restrict__ y)
{
    int node = blockIdx.x * 2 + (threadIdx.x >> 6);
    if (node >= N_NODES) return;
    int lane = threadIdx.x & 63;
    int c = lane << 1;   // channels c, c+1 (same head)

    v2f we0[8], we1[8];
    {
        const v2f* Wa = (const v2f*)(We + (size_t)c * EDGE_DIM);
        const v2f* Wb = (const v2f*)(We + (size_t)(c + 1) * EDGE_DIM);
#pragma unroll
        for (int q = 0; q < 8; ++q) { we0[q] = Wa[q]; we1[q] = Wb[q]; }
    }
    float2 atv = ((const float2*)att)[lane];
    v2f attv = {atv.x * LOG2E, atv.y * LOG2E};
    const v2f neg2 = {NEG_SLOPE, NEG_SLOPE};
    const float THR = 8.0f * LOG2E;

    int row  = rfl(offs[node]);
    int rend = rfl(offs[node + 1]);
    int last = rend - 1;
    v2f xrv = xr2[(size_t)node * 64 + lane];

    float m = -INFINITY, d = 0.f;
    v2f accv = {0.f, 0.f};

    auto attr_ptr = [&](int eid) -> const float4* {
        return (const float4*)((eid < N_EDGES) ? ea + (size_t)eid * EDGE_DIM
                                               : lattr + (size_t)(eid - N_EDGES) * EDGE_DIM);
    };

    // one edge's full compute; attrs arrive in SGPRs, xls in VGPRs. Packed chain.
    auto body = [&](float4 A0, float4 A1, float4 A2, float4 A3, v2f xls) {
        v2f a[8] = { {A0.x,A0.y},{A0.z,A0.w},{A1.x,A1.y},{A1.z,A1.w},
                     {A2.x,A2.y},{A2.z,A2.w},{A3.x,A3.y},{A3.z,A3.w} };
        v2f ee0 = {0.f,0.f}, ee1 = {0.f,0.f};
#pragma unroll
        for (int q = 0; q < 8; ++q) {
            ee0 = fma2(a[q], we0[q], ee0);
            ee1 = fma2(a[q], we1[q], ee1);
        }
        v2f v = xls + xrv;                              // pk_add
        v += (v2f){ee0.x + ee0.y, ee1.x + ee1.y};       // 2 adds + pk_add
        v2f vl = max2(v, v * neg2);                     // pk_mul + pk_max (leaky)
        v2f pp = vl * attv;                             // pk_mul (log2 domain)
        float pl = red16(pp.x + pp.y);                  // add + 4 DPP
        if (pl - m > THR) {                             // defer-max rescale
            float r_ = exp2f(m - pl);
            d *= r_; accv *= (v2f){r_, r_}; m = pl;
        }
        float w = exp2f(pl - m);
        d += w;
        accv = fma2((v2f){w, w}, xls, accv);            // pk_fma
    };

    // csr entries for edges row..row+3 (clamped), kept 4 ahead
    int2 se_a = csr[row];
    int2 se_b = csr[min(row + 1, last)];
    int2 se_c = csr[min(row + 2, last)];
    int2 se_d = csr[min(row + 3, last)];

    // depth-2 attr/xl slots from se_a, se_b
    const float4* apA = attr_ptr(se_a.y);
    float4 Aa0 = apA[0], Aa1 = apA[1], Aa2 = apA[2], Aa3 = apA[3];
    v2f xlA = xl2[(size_t)se_a.x * 64 + lane];
    const float4* apB = attr_ptr(se_b.y);
    float4 Ab0 = apB[0], Ab1 = apB[1], Ab2 = apB[2], Ab3 = apB[3];
    v2f xlB = xl2[(size_t)se_b.x * 64 + lane];

    int i = row;
    for (; i + 1 < rend; i += 2) {
        body(Aa0, Aa1, Aa2, Aa3, xlA);
        {   // refill slot A with edge i+2 (csr already resident in se_c)
            xlA = xl2[(size_t)se_c.x * 64 + lane];
            const float4* ap = attr_ptr(se_c.y);
            Aa0 = ap[0]; Aa1 = ap[1]; Aa2 = ap[2]; Aa3 = ap[3];
            se_c = csr[min(i + 4, last)];
        }
        body(Ab0, Ab1, Ab2, Ab3, xlB);
        {   // refill slot B with edge i+3 (csr already resident in se_d)
            xlB = xl2[(size_t)se_d.x * 64 + lane];
            const float4* ap = attr_ptr(se_d.y);
            Ab0 = ap[0]; Ab1 = ap[1]; Ab2 = ap[2]; Ab3 = ap[3];
            se_d = csr[min(i + 5, last)];
        }
    }
    if (i < rend) body(Aa0, Aa1, Aa2, Aa3, xlA);   // odd tail

    float2 bv = ((const float2*)bias)[lane];
    float o0 = accv.x / d + bv.x;
    float o1 = accv.y / d + bv.y;
    if (DO_ELU) {
        o0 = (o0 > 0.0f) ? o0 : (__expf(o0) - 1.0f);
        o1 = (o1 > 0.0f) ? o1 : (__expf(o1) - 1.0f);
    }
    *(float2*)(y + (size_t)node * 128 + c) = make_float2(o0, o1);
}

// ---------------- pool (segmented reduction over sorted batch) + head ----------------
__global__ __launch_bounds__(256) void pool_csr(const float* __restrict__ y,
                                                const int* __restrict__ batch,
                                                float* __restrict__ gsum,
                                                float* __restrict__ gcnt) {
    int base = blockIdx.x * 256;
    int t = threadIdx.x;
    int c = t & 127, h = t >> 7;
    int n = base + h;
    int end = min(base + 256, N_NODES);
    if (n >= end) return;
    float acc = 0.0f, cnt = 0.0f;
    int curb = batch[n];
    for (; n < end; n += 2) {
        int b = batch[n];
        if (b != curb) {
            atomicAdd(&gsum[curb * 128 + c], acc);
            if (c == 0) atomicAdd(&gcnt[curb], cnt);
            acc = 0.0f; cnt = 0.0f; curb = b;
        }
        acc += y[(long long)n * 128 + c];
        cnt += 1.0f;
    }
    atomicAdd(&gsum[curb * 128 + c], acc);
    if (c == 0) atomicAdd(&gcnt[curb], cnt);
}

__global__ __launch_bounds__(128) void head_kernel(
    const float* __restrict__ gsum, const float* __restrict__ gcnt,
    const float* __restrict__ Wg1, const float* __restrict__ bg1,
    const float* __restrict__ Wg2, const float* __restrict__ bg2,
    const float* __restrict__ Wp, const float* __restrict__ bp,
    float* __restrict__ out)
{
    int b = blockIdx.x;
    int j = threadIdx.x;
    __shared__ float g[128], h[128];
    float cntv = fmaxf(gcnt[b], 1.0f);
    g[j] = gsum[b * 128 + j] / cntv;
    __syncthreads();
    float a = bg1[j];
    for (int k = 0; k < 128; ++k) a += g[k] * Wg1[j * 128 + k];
    h[j] = fmaxf(a, 0.0f);
    __syncthreads();
    if (j < 15) {
        float o = bg2[j];
        for (int k = 0; k < 128; ++k) o += h[k] * Wg2[j * 128 + k];
        out[b * 25 + j] = o;
    }
    if (j >= 64 && j < 74) {
        int p = j - 64;
        float o = bp[p];
        for (int k = 0; k < 128; ++k) o += g[k] * Wp[p * 128 + k];
        out[b * 25 + 15 + p] = o;
    }
}

// ---------------- launch ----------------
extern "C" void kernel_launch(void* const* d_in, const int* in_sizes, int n_in,
                              void* d_out, int out_size, void* d_ws, size_t ws_size,
                              hipStream_t stream)
{
    const float* x     = (const float*)d_in[0];
    const int*   ei    = (const int*)  d_in[1];
    const float* ea    = (const float*)d_in[2];
    const int*   batch = (const int*)  d_in[3];
    const float* W1l = (const float*)d_in[4],  *b1l  = (const float*)d_in[5];
    const float* W1r = (const float*)d_in[6],  *b1r  = (const float*)d_in[7];
    const float* W1e = (const float*)d_in[8],  *att1 = (const float*)d_in[9];
    const float* bias1 = (const float*)d_in[10];
    const float* W2l = (const float*)d_in[11], *b2l  = (const float*)d_in[12];
    const float* W2r = (const float*)d_in[13], *b2r  = (const float*)d_in[14];
    const float* W2e = (const float*)d_in[15], *att2 = (const float*)d_in[16];
    const float* bias2 = (const float*)d_in[17];
    const float* Wg1 = (const float*)d_in[18], *bg1 = (const float*)d_in[19];
    const float* Wg2 = (const float*)d_in[20], *bg2 = (const float*)d_in[21];
    const float* Wp  = (const float*)d_in[22], *bp  = (const float*)d_in[23];
    const int* src = ei;
    const int* dst = ei + N_EDGES;

    // workspace layout (float units; all segment starts 8B-aligned)
    float* ws = (float*)d_ws;
    size_t o = 0;
    float* xl    = ws + o; o += (size_t)N_NODES * 128;
    float* xr    = ws + o; o += (size_t)N_NODES * 128;
    float* y     = ws + o; o += (size_t)N_NODES * 128;
    float* lattr = ws + o; o += (size_t)N_NODES * EDGE_DIM;
    int2* csr    = (int2*)(ws + o); o += (size_t)EN_TOT * 2;
    int* offs    = (int*)(ws + o); o += (size_t)N_NODES + 2;
    int* deg     = (int*)(ws + o); o += (size_t)N_NODES;          // start of zero region
    int* cursor  = (int*)(ws + o); o += (size_t)N_NODES;
    float* gsum  = ws + o; o += (size_t)BATCH * 128;
    float* gcnt  = ws + o; o += (size_t)BATCH;                     // end of zero region
    int* bsum    = (int*)(ws + o); o += 512;
    int* incl    = (int*)y;  // scan temp, dead before y is written

    float* out = (float*)d_out;

    // zero deg, cursor, gsum, gcnt (contiguous)
    long long nz = (long long)N_NODES * 2 + BATCH * 128 + BATCH;
    zero_kernel<<<512, 256, 0, stream>>>((float*)deg, nz);

    // ---- CSR build (shared by both layers) ----
    count_deg<<<(N_EDGES + 255) / 256, 256, 0, stream>>>(dst, deg);
    scan1<<<NB_SCAN, 256, 0, stream>>>(deg, incl, bsum);
    scan2<<<1, 512, 0, stream>>>(bsum);
    scan3<<<NB_SCAN, 256, 0, stream>>>(incl, deg, bsum, offs);
    scatter<<<(EN_TOT + 255) / 256, 256, 0, stream>>>(src, dst, offs, cursor, csr);
    loopattr_csr<<<(N_NODES + 3) / 4, 256, 0, stream>>>(offs, csr, ea, lattr);

    const int GAT_BLK = (N_NODES + 1) / 2;
    const int DL_BLK  = (N_NODES + 31) / 32;

    // ---- layer 1 ----
    dual_linear<32><<<DL_BLK, 256, 0, stream>>>(x, W1l, b1l, W1r, b1r, xl, xr, N_NODES);
    gat_fused<1><<<GAT_BLK, 128, 0, stream>>>(offs, csr, ea, lattr,
                                              W1e, att1, (const v2f*)xl, (const v2f*)xr, bias1, y);

    // ---- layer 2 ----
    dual_linear<128><<<DL_BLK, 256, 0, stream>>>(y, W2l, b2l, W2r, b2r, xl, xr, N_NODES);
    gat_fused<0><<<GAT_BLK, 128, 0, stream>>>(offs, csr, ea, lattr,
                                              W2e, att2, (const v2f*)xl, (const v2f*)xr, bias2, y);

    // ---- pool + head ----
    pool_csr<<<(N_NODES + 255) / 256, 256, 0, stream>>>(y, batch, gsum, gcnt);
    head_kernel<<<BATCH, 128, 0, stream>>>(gsum, gcnt, Wg1, bg1, Wg2, bg2, Wp, bp, out);
}

// Round 17
// 851.315 us; speedup vs baseline: 1.0106x; 1.0106x over previous
//
#include <hip/hip_runtime.h>
#include <math.h>

#define N_NODES 100000
#define N_EDGES 1600000
#define EN_TOT  (N_EDGES + N_NODES)
#define BATCH   16
#define EDGE_DIM 16
#define NEG_SLOPE 0.2f
#define NB_SCAN 391   // ceil(N_NODES/256)
#define LOG2E 1.44269504f

typedef float v2f __attribute__((ext_vector_type(2)));

__device__ __forceinline__ int rfl(int v) { return __builtin_amdgcn_readfirstlane(v); }

__device__ __forceinline__ v2f fma2(v2f a, v2f b, v2f c) {
#if __has_builtin(__builtin_elementwise_fma)
    return __builtin_elementwise_fma(a, b, c);
#else
    v2f r; r.x = fmaf(a.x, b.x, c.x); r.y = fmaf(a.y, b.y, c.y); return r;
#endif
}
__device__ __forceinline__ v2f max2(v2f a, v2f b) {
#if __has_builtin(__builtin_elementwise_max)
    return __builtin_elementwise_max(a, b);
#else
    v2f r; r.x = fmaxf(a.x, b.x); r.y = fmaxf(a.y, b.y); return r;
#endif
}

// DPP cross-lane add (VALU pipe, no DS round-trip / lgkmcnt stall).
template<int CTRL>
__device__ __forceinline__ float dpp_add(float p) {
    int t = __builtin_amdgcn_update_dpp(0, __float_as_int(p), CTRL, 0xF, 0xF, true);
    return p + __int_as_float(t);
}
// reduce-add over each 16-lane group, result in ALL 16 lanes.
__device__ __forceinline__ float red16(float p) {
    p = dpp_add<0xB1>(p);    // quad_perm [1,0,3,2] : xor1
    p = dpp_add<0x4E>(p);    // quad_perm [2,3,0,1] : xor2
    p = dpp_add<0x141>(p);   // row_half_mirror     : xor4-equivalent
    p = dpp_add<0x140>(p);   // row_mirror          : xor8-equivalent
    return p;
}

// ---------------- utility ----------------
__global__ void zero_kernel(float* __restrict__ p, long long n) {
    long long i = (long long)blockIdx.x * blockDim.x + threadIdx.x;
    long long stride = (long long)gridDim.x * blockDim.x;
    for (; i < n; i += stride) p[i] = 0.0f;
}

// ---------------- CSR build ----------------
// count_deg also records each edge's within-node rank (the atomic's return value)
// so scatter needs NO atomics at all.
__global__ void count_deg(const int* __restrict__ dst, int* __restrict__ deg,
                          int* __restrict__ rank) {
    int e = blockIdx.x * 256 + threadIdx.x;
    if (e < N_EDGES) rank[e] = atomicAdd(&deg[dst[e]], 1);
}

__global__ __launch_bounds__(256) void scan1(const int* __restrict__ deg,
                                             int* __restrict__ incl, int* __restrict__ bsum) {
    __shared__ int s[256];
    int n = blockIdx.x * 256 + threadIdx.x;
    int v = (n < N_NODES) ? deg[n] + 1 : 0;
    s[threadIdx.x] = v;
    __syncthreads();
    for (int off = 1; off < 256; off <<= 1) {
        int t = (threadIdx.x >= off) ? s[threadIdx.x - off] : 0;
        __syncthreads();
        s[threadIdx.x] += t;
        __syncthreads();
    }
    if (n < N_NODES) incl[n] = s[threadIdx.x];
    if (threadIdx.x == 255) bsum[blockIdx.x] = s[255];
}

__global__ __launch_bounds__(512) void scan2(int* __restrict__ bsum) {
    __shared__ int s[512];
    int t = threadIdx.x;
    int v = (t < NB_SCAN) ? bsum[t] : 0;
    s[t] = v;
    __syncthreads();
    for (int off = 1; off < 512; off <<= 1) {
        int u = (t >= off) ? s[t - off] : 0;
        __syncthreads();
        s[t] += u;
        __syncthreads();
    }
    if (t < NB_SCAN) bsum[t] = s[t] - v;  // exclusive block prefix
}

__global__ void scan3(const int* __restrict__ incl, const int* __restrict__ deg,
                      const int* __restrict__ bsum, int* __restrict__ offs) {
    int n = blockIdx.x * 256 + threadIdx.x;
    if (n < N_NODES) offs[n] = incl[n] - (deg[n] + 1) + bsum[blockIdx.x];
    if (n == 0) offs[N_NODES] = EN_TOT;
}

// scatter edges into CSR slots (packed {src, eid}) — atomic-free via rank[].
// self-loop goes in the LAST slot of each row.
__global__ void scatter(const int* __restrict__ src, const int* __restrict__ dst,
                        const int* __restrict__ offs, const int* __restrict__ rank,
                        int2* __restrict__ csr) {
    int e = blockIdx.x * 256 + threadIdx.x;
    if (e < N_EDGES) {
        csr[offs[dst[e]] + rank[e]] = make_int2(src[e], e);
    } else if (e < EN_TOT) {
        int n = e - N_EDGES;
        csr[offs[n + 1] - 1] = make_int2(n, N_EDGES + n);  // self-loop marker
    }
}

__global__ __launch_bounds__(256) void loopattr_csr(const int* __restrict__ offs,
                                                    const int2* __restrict__ csr,
                                                    const float* __restrict__ ea,
                                                    float* __restrict__ lattr) {
    int node = blockIdx.x * 4 + (threadIdx.x >> 6);
    if (node >= N_NODES) return;
    int lane = threadIdx.x & 63;
    int row = offs[node];
    int degn = offs[node + 1] - 1 - row;  // real edges only
    int k = lane & 15, grp = lane >> 4;
    float acc = 0.0f;
    for (int i = grp; i < degn; i += 4) {
        int eid = csr[row + i].y;
        acc += ea[(long long)eid * EDGE_DIM + k];
    }
    acc += __shfl_xor(acc, 16);
    acc += __shfl_xor(acc, 32);
    if (lane < 16) lattr[(long long)node * EDGE_DIM + k] = acc / fmaxf((float)degn, 1.0f);
}

// ---------------- dense transforms ----------------
// R10-proven structure; float4 LDS staging (ds_read_b128 broadcast).
// Scalar float acc[32] + tight kk loop (no ext-vector acc -> no R6 spill).
template<int K>
__global__ __launch_bounds__(256) void dual_linear(
    const float* __restrict__ in,
    const float* __restrict__ Wl, const float* __restrict__ bl,
    const float* __restrict__ Wr, const float* __restrict__ br,
    float* __restrict__ outl, float* __restrict__ outr, int N)
{
    constexpr int ROWS = 32;
    constexpr int K4 = K / 4;
    __shared__ float4 srow[ROWS][K4];
    int t = threadIdx.x;
    int base = blockIdx.x * ROWS;
    {
        const float4* in4 = (const float4*)in;
        for (int i = t; i < ROWS * K4; i += 256) {
            int r = i / K4, k = i - r * K4;
            int n = base + r;
            srow[r][k] = (n < N) ? in4[(size_t)n * K4 + k] : make_float4(0.f, 0.f, 0.f, 0.f);
        }
    }
    __syncthreads();
    const float* W  = (t < 128) ? Wl : Wr;
    const float* bb = (t < 128) ? bl : br;
    float* outp     = (t < 128) ? outl : outr;
    int j = t & 127;
    float bj = bb[j];
    float acc[ROWS];
#pragma unroll
    for (int r = 0; r < ROWS; ++r) acc[r] = bj;
    const float4* W4 = (const float4*)(W + (size_t)j * K);
    for (int kk = 0; kk < K4; ++kk) {
        float4 w = W4[kk];
#pragma unroll
        for (int r = 0; r < ROWS; ++r) {
            float4 a = srow[r][kk];   // wave-uniform -> ds_read_b128 broadcast
            acc[r] = fmaf(a.x, w.x, acc[r]);
            acc[r] = fmaf(a.y, w.y, acc[r]);
            acc[r] = fmaf(a.z, w.z, acc[r]);
            acc[r] = fmaf(a.w, w.w, acc[r]);
        }
    }
    for (int r = 0; r < ROWS; ++r) {
        int n = base + r;
        if (n < N) outp[(long long)n * 128 + j] = acc[r];
    }
}

// ---------------- fused GATv2 (depth-2 pipeline + csr-ahead-4, DPP reduce, pk body) ----
// 256-thread blocks, 4 nodes/block (R15-measured best occupancy).
// lane owns ADJACENT channels (2*lane, 2*lane+1), same head; one softmax state/lane;
// packed (VOP3P) elementwise chain; csr held 4 ahead in SGPRs; depth-2 attr/xl slots.
template<int DO_ELU>
__global__ __launch_bounds__(256) void gat_fused(
    const int* __restrict__ offs, const int2* __restrict__ csr,
    const float* __restrict__ ea, const float* __restrict__ lattr,
    const float* __restrict__ We, const float* __restrict__ att,
    const v2f* __restrict__ xl2, const v2f* __restrict__ xr2,
    const float* __restrict__ bias, float* __restrict__ y)
{
    int node = blockIdx.x * 4 + (threadIdx.x >> 6);
    if (node >= N_NODES) return;
    int lane = threadIdx.x & 63;
    int c = lane << 1;   // channels c, c+1 (same head)

    v2f we0[8], we1[8];
    {
        const v2f* Wa = (const v2f*)(We + (size_t)c * EDGE_DIM);
        const v2f* Wb = (const v2f*)(We + (size_t)(c + 1) * EDGE_DIM);
#pragma unroll
        for (int q = 0; q < 8; ++q) { we0[q] = Wa[q]; we1[q] = Wb[q]; }
    }
    float2 atv = ((const float2*)att)[lane];
    v2f attv = {atv.x * LOG2E, atv.y * LOG2E};
    const v2f neg2 = {NEG_SLOPE, NEG_SLOPE};
    const float THR = 8.0f * LOG2E;

    int row  = rfl(offs[node]);
    int rend = rfl(offs[node + 1]);
    int last = rend - 1;
    v2f xrv = xr2[(size_t)node * 64 + lane];

    float m = -INFINITY, d = 0.f;
    v2f accv = {0.f, 0.f};

    auto attr_ptr = [&](int eid) -> const float4* {
        return (const float4*)((eid < N_EDGES) ? ea + (size_t)eid * EDGE_DIM
                                               : lattr + (size_t)(eid - N_EDGES) * EDGE_DIM);
    };

    // one edge's full compute; attrs arrive in SGPRs, xls in VGPRs. Packed chain.
    auto body = [&](float4 A0, float4 A1, float4 A2, float4 A3, v2f xls) {
        v2f a[8] = { {A0.x,A0.y},{A0.z,A0.w},{A1.x,A1.y},{A1.z,A1.w},
                     {A2.x,A2.y},{A2.z,A2.w},{A3.x,A3.y},{A3.z,A3.w} };
        v2f ee0 = {0.f,0.f}, ee1 = {0.f,0.f};
#pragma unroll
        for (int q = 0; q < 8; ++q) {
            ee0 = fma2(a[q], we0[q], ee0);
            ee1 = fma2(a[q], we1[q], ee1);
        }
        v2f v = xls + xrv;                              // pk_add
        v += (v2f){ee0.x + ee0.y, ee1.x + ee1.y};       // 2 adds + pk_add
        v2f vl = max2(v, v * neg2);                     // pk_mul + pk_max (leaky)
        v2f pp = vl * attv;                             // pk_mul (log2 domain)
        float pl = red16(pp.x + pp.y);                  // add + 4 DPP
        if (pl - m > THR) {                             // defer-max rescale
            float r_ = exp2f(m - pl);
            d *= r_; accv *= (v2f){r_, r_}; m = pl;
        }
        float w = exp2f(pl - m);
        d += w;
        accv = fma2((v2f){w, w}, xls, accv);            // pk_fma
    };

    // csr entries for edges row..row+3 (clamped), kept 4 ahead
    int2 se_a = csr[row];
    int2 se_b = csr[min(row + 1, last)];
    int2 se_c = csr[min(row + 2, last)];
    int2 se_d = csr[min(row + 3, last)];

    // depth-2 attr/xl slots from se_a, se_b
    const float4* apA = attr_ptr(se_a.y);
    float4 Aa0 = apA[0], Aa1 = apA[1], Aa2 = apA[2], Aa3 = apA[3];
    v2f xlA = xl2[(size_t)se_a.x * 64 + lane];
    const float4* apB = attr_ptr(se_b.y);
    float4 Ab0 = apB[0], Ab1 = apB[1], Ab2 = apB[2], Ab3 = apB[3];
    v2f xlB = xl2[(size_t)se_b.x * 64 + lane];

    int i = row;
    for (; i + 1 < rend; i += 2) {
        body(Aa0, Aa1, Aa2, Aa3, xlA);
        {   // refill slot A with edge i+2 (csr already resident in se_c)
            xlA = xl2[(size_t)se_c.x * 64 + lane];
            const float4* ap = attr_ptr(se_c.y);
            Aa0 = ap[0]; Aa1 = ap[1]; Aa2 = ap[2]; Aa3 = ap[3];
            se_c = csr[min(i + 4, last)];
        }
        body(Ab0, Ab1, Ab2, Ab3, xlB);
        {   // refill slot B with edge i+3 (csr already resident in se_d)
            xlB = xl2[(size_t)se_d.x * 64 + lane];
            const float4* ap = attr_ptr(se_d.y);
            Ab0 = ap[0]; Ab1 = ap[1]; Ab2 = ap[2]; Ab3 = ap[3];
            se_d = csr[min(i + 5, last)];
        }
    }
    if (i < rend) body(Aa0, Aa1, Aa2, Aa3, xlA);   // odd tail

    float2 bv = ((const float2*)bias)[lane];
    float o0 = accv.x / d + bv.x;
    float o1 = accv.y / d + bv.y;
    if (DO_ELU) {
        o0 = (o0 > 0.0f) ? o0 : (__expf(o0) - 1.0f);
        o1 = (o1 > 0.0f) ? o1 : (__expf(o1) - 1.0f);
    }
    *(float2*)(y + (size_t)node * 128 + c) = make_float2(o0, o1);
}

// ---------------- pool (segmented reduction over sorted batch) + head ----------------
__global__ __launch_bounds__(256) void pool_csr(const float* __restrict__ y,
                                                const int* __restrict__ batch,
                                                float* __restrict__ gsum,
                                                float* __restrict__ gcnt) {
    int base = blockIdx.x * 256;
    int t = threadIdx.x;
    int c = t & 127, h = t >> 7;
    int n = base + h;
    int end = min(base + 256, N_NODES);
    if (n >= end) return;
    float acc = 0.0f, cnt = 0.0f;
    int curb = batch[n];
    for (; n < end; n += 2) {
        int b = batch[n];
        if (b != curb) {
            atomicAdd(&gsum[curb * 128 + c], acc);
            if (c == 0) atomicAdd(&gcnt[curb], cnt);
            acc = 0.0f; cnt = 0.0f; curb = b;
        }
        acc += y[(long long)n * 128 + c];
        cnt += 1.0f;
    }
    atomicAdd(&gsum[curb * 128 + c], acc);
    if (c == 0) atomicAdd(&gcnt[curb], cnt);
}

__global__ __launch_bounds__(128) void head_kernel(
    const float* __restrict__ gsum, const float* __restrict__ gcnt,
    const float* __restrict__ Wg1, const float* __restrict__ bg1,
    const float* __restrict__ Wg2, const float* __restrict__ bg2,
    const float* __restrict__ Wp, const float* __restrict__ bp,
    float* __restrict__ out)
{
    int b = blockIdx.x;
    int j = threadIdx.x;
    __shared__ float g[128], h[128];
    float cntv = fmaxf(gcnt[b], 1.0f);
    g[j] = gsum[b * 128 + j] / cntv;
    __syncthreads();
    float a = bg1[j];
    for (int k = 0; k < 128; ++k) a += g[k] * Wg1[j * 128 + k];
    h[j] = fmaxf(a, 0.0f);
    __syncthreads();
    if (j < 15) {
        float o = bg2[j];
        for (int k = 0; k < 128; ++k) o += h[k] * Wg2[j * 128 + k];
        out[b * 25 + j] = o;
    }
    if (j >= 64 && j < 74) {
        int p = j - 64;
        float o = bp[p];
        for (int k = 0; k < 128; ++k) o += g[k] * Wp[p * 128 + k];
        out[b * 25 + 15 + p] = o;
    }
}

// ---------------- launch ----------------
extern "C" void kernel_launch(void* const* d_in, const int* in_sizes, int n_in,
                              void* d_out, int out_size, void* d_ws, size_t ws_size,
                              hipStream_t stream)
{
    const float* x     = (const float*)d_in[0];
    const int*   ei    = (const int*)  d_in[1];
    const float* ea    = (const float*)d_in[2];
    const int*   batch = (const int*)  d_in[3];
    const float* W1l = (const float*)d_in[4],  *b1l  = (const float*)d_in[5];
    const float* W1r = (const float*)d_in[6],  *b1r  = (const float*)d_in[7];
    const float* W1e = (const float*)d_in[8],  *att1 = (const float*)d_in[9];
    const float* bias1 = (const float*)d_in[10];
    const float* W2l = (const float*)d_in[11], *b2l  = (const float*)d_in[12];
    const float* W2r = (const float*)d_in[13], *b2r  = (const float*)d_in[14];
    const float* W2e = (const float*)d_in[15], *att2 = (const float*)d_in[16];
    const float* bias2 = (const float*)d_in[17];
    const float* Wg1 = (const float*)d_in[18], *bg1 = (const float*)d_in[19];
    const float* Wg2 = (const float*)d_in[20], *bg2 = (const float*)d_in[21];
    const float* Wp  = (const float*)d_in[22], *bp  = (const float*)d_in[23];
    const int* src = ei;
    const int* dst = ei + N_EDGES;

    // workspace layout (float units; all segment starts 8B-aligned)
    float* ws = (float*)d_ws;
    size_t o = 0;
    float* xl    = ws + o; o += (size_t)N_NODES * 128;
    float* xr    = ws + o; o += (size_t)N_NODES * 128;
    float* y     = ws + o; o += (size_t)N_NODES * 128;
    float* lattr = ws + o; o += (size_t)N_NODES * EDGE_DIM;
    int2* csr    = (int2*)(ws + o); o += (size_t)EN_TOT * 2;
    int* offs    = (int*)(ws + o); o += (size_t)N_NODES + 2;
    int* rank    = (int*)(ws + o); o += (size_t)N_EDGES;
    int* deg     = (int*)(ws + o); o += (size_t)N_NODES;          // start of zero region
    float* gsum  = ws + o; o += (size_t)BATCH * 128;
    float* gcnt  = ws + o; o += (size_t)BATCH;                     // end of zero region
    int* bsum    = (int*)(ws + o); o += 512;
    int* incl    = (int*)y;  // scan temp, dead before y is written

    float* out = (float*)d_out;

    // zero deg, gsum, gcnt (contiguous)
    long long nz = (long long)N_NODES + BATCH * 128 + BATCH;
    zero_kernel<<<512, 256, 0, stream>>>((float*)deg, nz);

    // ---- CSR build (shared by both layers) ----
    count_deg<<<(N_EDGES + 255) / 256, 256, 0, stream>>>(dst, deg, rank);
    scan1<<<NB_SCAN, 256, 0, stream>>>(deg, incl, bsum);
    scan2<<<1, 512, 0, stream>>>(bsum);
    scan3<<<NB_SCAN, 256, 0, stream>>>(incl, deg, bsum, offs);
    scatter<<<(EN_TOT + 255) / 256, 256, 0, stream>>>(src, dst, offs, rank, csr);
    loopattr_csr<<<(N_NODES + 3) / 4, 256, 0, stream>>>(offs, csr, ea, lattr);

    const int GAT_BLK = (N_NODES + 3) / 4;
    const int DL_BLK  = (N_NODES + 31) / 32;

    // ---- layer 1 ----
    dual_linear<32><<<DL_BLK, 256, 0, stream>>>(x, W1l, b1l, W1r, b1r, xl, xr, N_NODES);
    gat_fused<1><<<GAT_BLK, 256, 0, stream>>>(offs, csr, ea, lattr,
                                              W1e, att1, (const v2f*)xl, (const v2f*)xr, bias1, y);

    // ---- layer 2 ----
    dual_linear<128><<<DL_BLK, 256, 0, stream>>>(y, W2l, b2l, W2r, b2r, xl, xr, N_NODES);
    gat_fused<0><<<GAT_BLK, 256, 0, stream>>>(offs, csr, ea, lattr,
                                              W2e, att2, (const v2f*)xl, (const v2f*)xr, bias2, y);

    // ---- pool + head ----
    pool_csr<<<(N_NODES + 255) / 256, 256, 0, stream>>>(y, batch, gsum, gcnt);
    head_kernel<<<BATCH, 128, 0, stream>>>(gsum, gcnt, Wg1, bg1, Wg2, bg2, Wp, bp, out);
}

// Round 18
// 816.002 us; speedup vs baseline: 1.0544x; 1.0433x over previous
//
#include <hip/hip_runtime.h>
#include <math.h>

#define N_NODES 100000
#define N_EDGES 1600000
#define EN_TOT  (N_EDGES + N_NODES)
#define BATCH   16
#define EDGE_DIM 16
#define NEG_SLOPE 0.2f
#define NB_SCAN 391   // ceil(N_NODES/256)
#define LOG2E 1.44269504f

typedef float v2f __attribute__((ext_vector_type(2)));

__device__ __forceinline__ int rfl(int v) { return __builtin_amdgcn_readfirstlane(v); }

__device__ __forceinline__ v2f fma2(v2f a, v2f b, v2f c) {
#if __has_builtin(__builtin_elementwise_fma)
    return __builtin_elementwise_fma(a, b, c);
#else
    v2f r; r.x = fmaf(a.x, b.x, c.x); r.y = fmaf(a.y, b.y, c.y); return r;
#endif
}

// DPP cross-lane add (VALU pipe, no DS round-trip / lgkmcnt stall).
template<int CTRL>
__device__ __forceinline__ float dpp_add(float p) {
    int t = __builtin_amdgcn_update_dpp(0, __float_as_int(p), CTRL, 0xF, 0xF, true);
    return p + __int_as_float(t);
}
// reduce-add over each 16-lane group, result in ALL 16 lanes.
__device__ __forceinline__ float red16(float p) {
    p = dpp_add<0xB1>(p);    // quad_perm [1,0,3,2] : xor1
    p = dpp_add<0x4E>(p);    // quad_perm [2,3,0,1] : xor2
    p = dpp_add<0x141>(p);   // row_half_mirror     : xor4-equivalent
    p = dpp_add<0x140>(p);   // row_mirror          : xor8-equivalent
    return p;
}

// ---------------- utility ----------------
__global__ void zero_kernel(float* __restrict__ p, long long n) {
    long long i = (long long)blockIdx.x * blockDim.x + threadIdx.x;
    long long stride = (long long)gridDim.x * blockDim.x;
    for (; i < n; i += stride) p[i] = 0.0f;
}

// ---------------- CSR build ----------------
// count_deg also records each edge's within-node rank (the atomic's return value)
// so scatter needs NO atomics at all.
__global__ void count_deg(const int* __restrict__ dst, int* __restrict__ deg,
                          int* __restrict__ rank) {
    int e = blockIdx.x * 256 + threadIdx.x;
    if (e < N_EDGES) rank[e] = atomicAdd(&deg[dst[e]], 1);
}

__global__ __launch_bounds__(256) void scan1(const int* __restrict__ deg,
                                             int* __restrict__ incl, int* __restrict__ bsum) {
    __shared__ int s[256];
    int n = blockIdx.x * 256 + threadIdx.x;
    int v = (n < N_NODES) ? deg[n] + 1 : 0;
    s[threadIdx.x] = v;
    __syncthreads();
    for (int off = 1; off < 256; off <<= 1) {
        int t = (threadIdx.x >= off) ? s[threadIdx.x - off] : 0;
        __syncthreads();
        s[threadIdx.x] += t;
        __syncthreads();
    }
    if (n < N_NODES) incl[n] = s[threadIdx.x];
    if (threadIdx.x == 255) bsum[blockIdx.x] = s[255];
}

__global__ __launch_bounds__(512) void scan2(int* __restrict__ bsum) {
    __shared__ int s[512];
    int t = threadIdx.x;
    int v = (t < NB_SCAN) ? bsum[t] : 0;
    s[t] = v;
    __syncthreads();
    for (int off = 1; off < 512; off <<= 1) {
        int u = (t >= off) ? s[t - off] : 0;
        __syncthreads();
        s[t] += u;
        __syncthreads();
    }
    if (t < NB_SCAN) bsum[t] = s[t] - v;  // exclusive block prefix
}

__global__ void scan3(const int* __restrict__ incl, const int* __restrict__ deg,
                      const int* __restrict__ bsum, int* __restrict__ offs) {
    int n = blockIdx.x * 256 + threadIdx.x;
    if (n < N_NODES) offs[n] = incl[n] - (deg[n] + 1) + bsum[blockIdx.x];
    if (n == 0) offs[N_NODES] = EN_TOT;
}

// scatter edges into CSR slots (packed {src, eid}) — atomic-free via rank[].
// self-loop goes in the LAST slot of each row.
__global__ void scatter(const int* __restrict__ src, const int* __restrict__ dst,
                        const int* __restrict__ offs, const int* __restrict__ rank,
                        int2* __restrict__ csr) {
    int e = blockIdx.x * 256 + threadIdx.x;
    if (e < N_EDGES) {
        csr[offs[dst[e]] + rank[e]] = make_int2(src[e], e);
    } else if (e < EN_TOT) {
        int n = e - N_EDGES;
        csr[offs[n + 1] - 1] = make_int2(n, N_EDGES + n);  // self-loop marker
    }
}

__global__ __launch_bounds__(256) void loopattr_csr(const int* __restrict__ offs,
                                                    const int2* __restrict__ csr,
                                                    const float* __restrict__ ea,
                                                    float* __restrict__ lattr) {
    int node = blockIdx.x * 4 + (threadIdx.x >> 6);
    if (node >= N_NODES) return;
    int lane = threadIdx.x & 63;
    int row = offs[node];
    int degn = offs[node + 1] - 1 - row;  // real edges only
    int k = lane & 15, grp = lane >> 4;
    float acc = 0.0f;
    for (int i = grp; i < degn; i += 4) {
        int eid = csr[row + i].y;
        acc += ea[(long long)eid * EDGE_DIM + k];
    }
    acc += __shfl_xor(acc, 16);
    acc += __shfl_xor(acc, 32);
    if (lane < 16) lattr[(long long)node * EDGE_DIM + k] = acc / fmaxf((float)degn, 1.0f);
}

// ---------------- dense transforms ----------------
// R10-proven structure; float4 LDS staging (ds_read_b128 broadcast).
// Scalar float acc[32] + tight kk loop (no ext-vector acc -> no R6 spill).
template<int K>
__global__ __launch_bounds__(256) void dual_linear(
    const float* __restrict__ in,
    const float* __restrict__ Wl, const float* __restrict__ bl,
    const float* __restrict__ Wr, const float* __restrict__ br,
    float* __restrict__ outl, float* __restrict__ outr, int N)
{
    constexpr int ROWS = 32;
    constexpr int K4 = K / 4;
    __shared__ float4 srow[ROWS][K4];
    int t = threadIdx.x;
    int base = blockIdx.x * ROWS;
    {
        const float4* in4 = (const float4*)in;
        for (int i = t; i < ROWS * K4; i += 256) {
            int r = i / K4, k = i - r * K4;
            int n = base + r;
            srow[r][k] = (n < N) ? in4[(size_t)n * K4 + k] : make_float4(0.f, 0.f, 0.f, 0.f);
        }
    }
    __syncthreads();
    const float* W  = (t < 128) ? Wl : Wr;
    const float* bb = (t < 128) ? bl : br;
    float* outp     = (t < 128) ? outl : outr;
    int j = t & 127;
    float bj = bb[j];
    float acc[ROWS];
#pragma unroll
    for (int r = 0; r < ROWS; ++r) acc[r] = bj;
    const float4* W4 = (const float4*)(W + (size_t)j * K);
    for (int kk = 0; kk < K4; ++kk) {
        float4 w = W4[kk];
#pragma unroll
        for (int r = 0; r < ROWS; ++r) {
            float4 a = srow[r][kk];   // wave-uniform -> ds_read_b128 broadcast
            acc[r] = fmaf(a.x, w.x, acc[r]);
            acc[r] = fmaf(a.y, w.y, acc[r]);
            acc[r] = fmaf(a.z, w.z, acc[r]);
            acc[r] = fmaf(a.w, w.w, acc[r]);
        }
    }
    for (int r = 0; r < ROWS; ++r) {
        int n = base + r;
        if (n < N) outp[(long long)n * 128 + j] = acc[r];
    }
}

// ---------------- fused GATv2 (R15-measured-best: scalar body, 256-thr, depth-2 +
// csr-ahead-4, DPP reduce) ----------------
// one wave per node (4 nodes/block); lane owns ADJACENT channels (2*lane, 2*lane+1),
// same head (head = lane>>4). One softmax state per lane, 4-stage DPP reduce.
template<int DO_ELU>
__global__ __launch_bounds__(256) void gat_fused(
    const int* __restrict__ offs, const int2* __restrict__ csr,
    const float* __restrict__ ea, const float* __restrict__ lattr,
    const float* __restrict__ We, const float* __restrict__ att,
    const v2f* __restrict__ xl2, const v2f* __restrict__ xr2,
    const float* __restrict__ bias, float* __restrict__ y)
{
    int node = blockIdx.x * 4 + (threadIdx.x >> 6);
    if (node >= N_NODES) return;
    int lane = threadIdx.x & 63;
    int c = lane << 1;   // channels c, c+1 (same head)

    v2f we0[8], we1[8];
    {
        const v2f* Wa = (const v2f*)(We + (size_t)c * EDGE_DIM);
        const v2f* Wb = (const v2f*)(We + (size_t)(c + 1) * EDGE_DIM);
#pragma unroll
        for (int q = 0; q < 8; ++q) { we0[q] = Wa[q]; we1[q] = Wb[q]; }
    }
    float2 atv = ((const float2*)att)[lane];
    float att0 = atv.x * LOG2E, att1 = atv.y * LOG2E;
    const float THR = 8.0f * LOG2E;

    int row  = rfl(offs[node]);
    int rend = rfl(offs[node + 1]);
    int last = rend - 1;
    v2f xrv = xr2[(size_t)node * 64 + lane];

    float m = -INFINITY, d = 0.f, acc0 = 0.f, acc1 = 0.f;

    auto attr_ptr = [&](int eid) -> const float4* {
        return (const float4*)((eid < N_EDGES) ? ea + (size_t)eid * EDGE_DIM
                                               : lattr + (size_t)(eid - N_EDGES) * EDGE_DIM);
    };

    // one edge's full compute; attrs arrive in SGPRs, xls in VGPRs
    auto body = [&](float4 A0, float4 A1, float4 A2, float4 A3, v2f xls) {
        v2f a[8] = { {A0.x,A0.y},{A0.z,A0.w},{A1.x,A1.y},{A1.z,A1.w},
                     {A2.x,A2.y},{A2.z,A2.w},{A3.x,A3.y},{A3.z,A3.w} };
        v2f ee0 = {0.f,0.f}, ee1 = {0.f,0.f};
#pragma unroll
        for (int q = 0; q < 8; ++q) {
            ee0 = fma2(a[q], we0[q], ee0);
            ee1 = fma2(a[q], we1[q], ee1);
        }
        float v0 = xls.x + xrv.x + ee0.x + ee0.y;
        float v1 = xls.y + xrv.y + ee1.x + ee1.y;
        v0 = fmaxf(v0, NEG_SLOPE * v0);   // leaky-relu, exact for slope<1
        v1 = fmaxf(v1, NEG_SLOPE * v1);
        float pl = red16(fmaf(v0, att0, v1 * att1));  // head logit, log2 domain
        if (pl - m > THR) { float r_ = exp2f(m - pl); d *= r_; acc0 *= r_; acc1 *= r_; m = pl; }
        float w = exp2f(pl - m);
        d += w;
        acc0 = fmaf(w, xls.x, acc0);
        acc1 = fmaf(w, xls.y, acc1);
    };

    // csr entries for edges row..row+3 (clamped), kept 4 ahead
    int2 se_a = csr[row];
    int2 se_b = csr[min(row + 1, last)];
    int2 se_c = csr[min(row + 2, last)];
    int2 se_d = csr[min(row + 3, last)];

    // depth-2 attr/xl slots from se_a, se_b
    const float4* apA = attr_ptr(se_a.y);
    float4 Aa0 = apA[0], Aa1 = apA[1], Aa2 = apA[2], Aa3 = apA[3];
    v2f xlA = xl2[(size_t)se_a.x * 64 + lane];
    const float4* apB = attr_ptr(se_b.y);
    float4 Ab0 = apB[0], Ab1 = apB[1], Ab2 = apB[2], Ab3 = apB[3];
    v2f xlB = xl2[(size_t)se_b.x * 64 + lane];

    int i = row;
    for (; i + 1 < rend; i += 2) {
        body(Aa0, Aa1, Aa2, Aa3, xlA);
        {   // refill slot A with edge i+2 (csr already resident in se_c)
            xlA = xl2[(size_t)se_c.x * 64 + lane];
            const float4* ap = attr_ptr(se_c.y);
            Aa0 = ap[0]; Aa1 = ap[1]; Aa2 = ap[2]; Aa3 = ap[3];
            se_c = csr[min(i + 4, last)];
        }
        body(Ab0, Ab1, Ab2, Ab3, xlB);
        {   // refill slot B with edge i+3 (csr already resident in se_d)
            xlB = xl2[(size_t)se_d.x * 64 + lane];
            const float4* ap = attr_ptr(se_d.y);
            Ab0 = ap[0]; Ab1 = ap[1]; Ab2 = ap[2]; Ab3 = ap[3];
            se_d = csr[min(i + 5, last)];
        }
    }
    if (i < rend) body(Aa0, Aa1, Aa2, Aa3, xlA);   // odd tail

    float2 bv = ((const float2*)bias)[lane];
    float o0 = acc0 / d + bv.x;
    float o1 = acc1 / d + bv.y;
    if (DO_ELU) {
        o0 = (o0 > 0.0f) ? o0 : (__expf(o0) - 1.0f);
        o1 = (o1 > 0.0f) ? o1 : (__expf(o1) - 1.0f);
    }
    *(float2*)(y + (size_t)node * 128 + c) = make_float2(o0, o1);
}

// ---------------- pool (segmented reduction over sorted batch) + head ----------------
__global__ __launch_bounds__(256) void pool_csr(const float* __restrict__ y,
                                                const int* __restrict__ batch,
                                                float* __restrict__ gsum,
                                                float* __restrict__ gcnt) {
    int base = blockIdx.x * 256;
    int t = threadIdx.x;
    int c = t & 127, h = t >> 7;
    int n = base + h;
    int end = min(base + 256, N_NODES);
    if (n >= end) return;
    float acc = 0.0f, cnt = 0.0f;
    int curb = batch[n];
    for (; n < end; n += 2) {
        int b = batch[n];
        if (b != curb) {
            atomicAdd(&gsum[curb * 128 + c], acc);
            if (c == 0) atomicAdd(&gcnt[curb], cnt);
            acc = 0.0f; cnt = 0.0f; curb = b;
        }
        acc += y[(long long)n * 128 + c];
        cnt += 1.0f;
    }
    atomicAdd(&gsum[curb * 128 + c], acc);
    if (c == 0) atomicAdd(&gcnt[curb], cnt);
}

__global__ __launch_bounds__(128) void head_kernel(
    const float* __restrict__ gsum, const float* __restrict__ gcnt,
    const float* __restrict__ Wg1, const float* __restrict__ bg1,
    const float* __restrict__ Wg2, const float* __restrict__ bg2,
    const float* __restrict__ Wp, const float* __restrict__ bp,
    float* __restrict__ out)
{
    int b = blockIdx.x;
    int j = threadIdx.x;
    __shared__ float g[128], h[128];
    float cntv = fmaxf(gcnt[b], 1.0f);
    g[j] = gsum[b * 128 + j] / cntv;
    __syncthreads();
    float a = bg1[j];
    for (int k = 0; k < 128; ++k) a += g[k] * Wg1[j * 128 + k];
    h[j] = fmaxf(a, 0.0f);
    __syncthreads();
    if (j < 15) {
        float o = bg2[j];
        for (int k = 0; k < 128; ++k) o += h[k] * Wg2[j * 128 + k];
        out[b * 25 + j] = o;
    }
    if (j >= 64 && j < 74) {
        int p = j - 64;
        float o = bp[p];
        for (int k = 0; k < 128; ++k) o += g[k] * Wp[p * 128 + k];
        out[b * 25 + 15 + p] = o;
    }
}

// ---------------- launch ----------------
extern "C" void kernel_launch(void* const* d_in, const int* in_sizes, int n_in,
                              void* d_out, int out_size, void* d_ws, size_t ws_size,
                              hipStream_t stream)
{
    const float* x     = (const float*)d_in[0];
    const int*   ei    = (const int*)  d_in[1];
    const float* ea    = (const float*)d_in[2];
    const int*   batch = (const int*)  d_in[3];
    const float* W1l = (const float*)d_in[4],  *b1l  = (const float*)d_in[5];
    const float* W1r = (const float*)d_in[6],  *b1r  = (const float*)d_in[7];
    const float* W1e = (const float*)d_in[8],  *att1 = (const float*)d_in[9];
    const float* bias1 = (const float*)d_in[10];
    const float* W2l = (const float*)d_in[11], *b2l  = (const float*)d_in[12];
    const float* W2r = (const float*)d_in[13], *b2r  = (const float*)d_in[14];
    const float* W2e = (const float*)d_in[15], *att2 = (const float*)d_in[16];
    const float* bias2 = (const float*)d_in[17];
    const float* Wg1 = (const float*)d_in[18], *bg1 = (const float*)d_in[19];
    const float* Wg2 = (const float*)d_in[20], *bg2 = (const float*)d_in[21];
    const float* Wp  = (const float*)d_in[22], *bp  = (const float*)d_in[23];
    const int* src = ei;
    const int* dst = ei + N_EDGES;

    // workspace layout (float units; all segment starts 8B-aligned)
    float* ws = (float*)d_ws;
    size_t o = 0;
    float* xl    = ws + o; o += (size_t)N_NODES * 128;
    float* xr    = ws + o; o += (size_t)N_NODES * 128;
    float* y     = ws + o; o += (size_t)N_NODES * 128;
    float* lattr = ws + o; o += (size_t)N_NODES * EDGE_DIM;
    int2* csr    = (int2*)(ws + o); o += (size_t)EN_TOT * 2;
    int* offs    = (int*)(ws + o); o += (size_t)N_NODES + 2;
    int* rank    = (int*)(ws + o); o += (size_t)N_EDGES;
    int* deg     = (int*)(ws + o); o += (size_t)N_NODES;          // start of zero region
    float* gsum  = ws + o; o += (size_t)BATCH * 128;
    float* gcnt  = ws + o; o += (size_t)BATCH;                     // end of zero region
    int* bsum    = (int*)(ws + o); o += 512;
    int* incl    = (int*)y;  // scan temp, dead before y is written

    float* out = (float*)d_out;

    // zero deg, gsum, gcnt (contiguous)
    long long nz = (long long)N_NODES + BATCH * 128 + BATCH;
    zero_kernel<<<512, 256, 0, stream>>>((float*)deg, nz);

    // ---- CSR build (shared by both layers) ----
    count_deg<<<(N_EDGES + 255) / 256, 256, 0, stream>>>(dst, deg, rank);
    scan1<<<NB_SCAN, 256, 0, stream>>>(deg, incl, bsum);
    scan2<<<1, 512, 0, stream>>>(bsum);
    scan3<<<NB_SCAN, 256, 0, stream>>>(incl, deg, bsum, offs);
    scatter<<<(EN_TOT + 255) / 256, 256, 0, stream>>>(src, dst, offs, rank, csr);
    loopattr_csr<<<(N_NODES + 3) / 4, 256, 0, stream>>>(offs, csr, ea, lattr);

    const int GAT_BLK = (N_NODES + 3) / 4;
    const int DL_BLK  = (N_NODES + 31) / 32;

    // ---- layer 1 ----
    dual_linear<32><<<DL_BLK, 256, 0, stream>>>(x, W1l, b1l, W1r, b1r, xl, xr, N_NODES);
    gat_fused<1><<<GAT_BLK, 256, 0, stream>>>(offs, csr, ea, lattr,
                                              W1e, att1, (const v2f*)xl, (const v2f*)xr, bias1, y);

    // ---- layer 2 ----
    dual_linear<128><<<DL_BLK, 256, 0, stream>>>(y, W2l, b2l, W2r, b2r, xl, xr, N_NODES);
    gat_fused<0><<<GAT_BLK, 256, 0, stream>>>(offs, csr, ea, lattr,
                                              W2e, att2, (const v2f*)xl, (const v2f*)xr, bias2, y);

    // ---- pool + head ----
    pool_csr<<<(N_NODES + 255) / 256, 256, 0, stream>>>(y, batch, gsum, gcnt);
    head_kernel<<<BATCH, 128, 0, stream>>>(gsum, gcnt, Wg1, bg1, Wg2, bg2, Wp, bp, out);
}

// Round 19
// 778.851 us; speedup vs baseline: 1.1047x; 1.0477x over previous
//
#include <hip/hip_runtime.h>
#include <math.h>

#define N_NODES 100000
#define N_EDGES 1600000
#define EN_TOT  (N_EDGES + N_NODES)
#define BATCH   16
#define EDGE_DIM 16
#define NEG_SLOPE 0.2f
#define NB_SCAN 391   // ceil(N_NODES/256)
#define LOG2E 1.44269504f

typedef float v2f __attribute__((ext_vector_type(2)));

__device__ __forceinline__ int rfl(int v) { return __builtin_amdgcn_readfirstlane(v); }

__device__ __forceinline__ v2f fma2(v2f a, v2f b, v2f c) {
#if __has_builtin(__builtin_elementwise_fma)
    return __builtin_elementwise_fma(a, b, c);
#else
    v2f r; r.x = fmaf(a.x, b.x, c.x); r.y = fmaf(a.y, b.y, c.y); return r;
#endif
}

// DPP cross-lane add (VALU pipe, no DS round-trip / lgkmcnt stall).
template<int CTRL>
__device__ __forceinline__ float dpp_add(float p) {
    int t = __builtin_amdgcn_update_dpp(0, __float_as_int(p), CTRL, 0xF, 0xF, true);
    return p + __int_as_float(t);
}
// reduce-add over each 16-lane group, result in ALL 16 lanes.
__device__ __forceinline__ float red16(float p) {
    p = dpp_add<0xB1>(p);    // quad_perm [1,0,3,2] : xor1
    p = dpp_add<0x4E>(p);    // quad_perm [2,3,0,1] : xor2
    p = dpp_add<0x141>(p);   // row_half_mirror     : xor4-equivalent
    p = dpp_add<0x140>(p);   // row_mirror          : xor8-equivalent
    return p;
}

// ---------------- utility ----------------
__global__ void zero_kernel(float* __restrict__ p, long long n) {
    long long i = (long long)blockIdx.x * blockDim.x + threadIdx.x;
    long long stride = (long long)gridDim.x * blockDim.x;
    for (; i < n; i += stride) p[i] = 0.0f;
}

// ---------------- CSR build ----------------
// count_deg also records each edge's within-node rank (the atomic's return value)
// so scatter needs NO atomics at all.
__global__ void count_deg(const int* __restrict__ dst, int* __restrict__ deg,
                          int* __restrict__ rank) {
    int e = blockIdx.x * 256 + threadIdx.x;
    if (e < N_EDGES) rank[e] = atomicAdd(&deg[dst[e]], 1);
}

__global__ __launch_bounds__(256) void scan1(const int* __restrict__ deg,
                                             int* __restrict__ incl, int* __restrict__ bsum) {
    __shared__ int s[256];
    int n = blockIdx.x * 256 + threadIdx.x;
    int v = (n < N_NODES) ? deg[n] + 1 : 0;
    s[threadIdx.x] = v;
    __syncthreads();
    for (int off = 1; off < 256; off <<= 1) {
        int t = (threadIdx.x >= off) ? s[threadIdx.x - off] : 0;
        __syncthreads();
        s[threadIdx.x] += t;
        __syncthreads();
    }
    if (n < N_NODES) incl[n] = s[threadIdx.x];
    if (threadIdx.x == 255) bsum[blockIdx.x] = s[255];
}

__global__ __launch_bounds__(512) void scan2(int* __restrict__ bsum) {
    __shared__ int s[512];
    int t = threadIdx.x;
    int v = (t < NB_SCAN) ? bsum[t] : 0;
    s[t] = v;
    __syncthreads();
    for (int off = 1; off < 512; off <<= 1) {
        int u = (t >= off) ? s[t - off] : 0;
        __syncthreads();
        s[t] += u;
        __syncthreads();
    }
    if (t < NB_SCAN) bsum[t] = s[t] - v;  // exclusive block prefix
}

__global__ void scan3(const int* __restrict__ incl, const int* __restrict__ deg,
                      const int* __restrict__ bsum, int* __restrict__ offs) {
    int n = blockIdx.x * 256 + threadIdx.x;
    if (n < N_NODES) offs[n] = incl[n] - (deg[n] + 1) + bsum[blockIdx.x];
    if (n == 0) offs[N_NODES] = EN_TOT;
}

// scatter real edges into CSR slots (packed {src, eid}) — atomic-free via rank[].
// Row layout: [offs[n], offs[n+1]-1) = real edges; slot offs[n+1]-1 reserved
// (self-loop, handled analytically in gat_fused — never read).
__global__ void scatter(const int* __restrict__ src, const int* __restrict__ dst,
                        const int* __restrict__ offs, const int* __restrict__ rank,
                        int2* __restrict__ csr) {
    int e = blockIdx.x * 256 + threadIdx.x;
    if (e < N_EDGES) {
        csr[offs[dst[e]] + rank[e]] = make_int2(src[e], e);
    }
}

// ---------------- dense transforms ----------------
// R10-proven structure; float4 LDS staging (ds_read_b128 broadcast).
// Scalar float acc[32] + tight kk loop (no ext-vector acc -> no R6 spill).
template<int K>
__global__ __launch_bounds__(256) void dual_linear(
    const float* __restrict__ in,
    const float* __restrict__ Wl, const float* __restrict__ bl,
    const float* __restrict__ Wr, const float* __restrict__ br,
    float* __restrict__ outl, float* __restrict__ outr, int N)
{
    constexpr int ROWS = 32;
    constexpr int K4 = K / 4;
    __shared__ float4 srow[ROWS][K4];
    int t = threadIdx.x;
    int base = blockIdx.x * ROWS;
    {
        const float4* in4 = (const float4*)in;
        for (int i = t; i < ROWS * K4; i += 256) {
            int r = i / K4, k = i - r * K4;
            int n = base + r;
            srow[r][k] = (n < N) ? in4[(size_t)n * K4 + k] : make_float4(0.f, 0.f, 0.f, 0.f);
        }
    }
    __syncthreads();
    const float* W  = (t < 128) ? Wl : Wr;
    const float* bb = (t < 128) ? bl : br;
    float* outp     = (t < 128) ? outl : outr;
    int j = t & 127;
    float bj = bb[j];
    float acc[ROWS];
#pragma unroll
    for (int r = 0; r < ROWS; ++r) acc[r] = bj;
    const float4* W4 = (const float4*)(W + (size_t)j * K);
    for (int kk = 0; kk < K4; ++kk) {
        float4 w = W4[kk];
#pragma unroll
        for (int r = 0; r < ROWS; ++r) {
            float4 a = srow[r][kk];   // wave-uniform -> ds_read_b128 broadcast
            acc[r] = fmaf(a.x, w.x, acc[r]);
            acc[r] = fmaf(a.y, w.y, acc[r]);
            acc[r] = fmaf(a.z, w.z, acc[r]);
            acc[r] = fmaf(a.w, w.w, acc[r]);
        }
    }
    for (int r = 0; r < ROWS; ++r) {
        int n = base + r;
        if (n < N) outp[(long long)n * 128 + j] = acc[r];
    }
}

// ---------------- fused GATv2 ----------------
// R18 structure (scalar body, 256-thr, depth-2 + csr-ahead-4, DPP reduce) with the
// self-loop handled ANALYTICALLY: since ee = attr @ We.T is linear in attr, the
// self-loop's ee (attr = mean of incoming edge attrs) equals the running mean of
// the real edges' ee values — accumulated in registers, no lattr, no loopattr pass.
// All pipelined edges are real -> attr pointer is unconditional (ea + eid*16).
template<int DO_ELU>
__global__ __launch_bounds__(256) void gat_fused(
    const int* __restrict__ offs, const int2* __restrict__ csr,
    const float* __restrict__ ea,
    const float* __restrict__ We, const float* __restrict__ att,
    const v2f* __restrict__ xl2, const v2f* __restrict__ xr2,
    const float* __restrict__ bias, float* __restrict__ y)
{
    int node = blockIdx.x * 4 + (threadIdx.x >> 6);
    if (node >= N_NODES) return;
    int lane = threadIdx.x & 63;
    int c = lane << 1;   // channels c, c+1 (same head)

    v2f we0[8], we1[8];
    {
        const v2f* Wa = (const v2f*)(We + (size_t)c * EDGE_DIM);
        const v2f* Wb = (const v2f*)(We + (size_t)(c + 1) * EDGE_DIM);
#pragma unroll
        for (int q = 0; q < 8; ++q) { we0[q] = Wa[q]; we1[q] = Wb[q]; }
    }
    float2 atv = ((const float2*)att)[lane];
    float att0 = atv.x * LOG2E, att1 = atv.y * LOG2E;
    const float THR = 8.0f * LOG2E;

    int row  = rfl(offs[node]);
    int rend = rfl(offs[node + 1]);
    int degn  = rend - 1 - row;   // real edges
    int rlast = rend - 2;         // last real edge index
    v2f xrv = xr2[(size_t)node * 64 + lane];

    float m = -INFINITY, d = 0.f, acc0 = 0.f, acc1 = 0.f;
    v2f eesum0 = {0.f, 0.f}, eesum1 = {0.f, 0.f};

    // one real edge's full compute; attrs arrive in SGPRs, xls in VGPRs
    auto body = [&](float4 A0, float4 A1, float4 A2, float4 A3, v2f xls) {
        v2f a[8] = { {A0.x,A0.y},{A0.z,A0.w},{A1.x,A1.y},{A1.z,A1.w},
                     {A2.x,A2.y},{A2.z,A2.w},{A3.x,A3.y},{A3.z,A3.w} };
        v2f ee0 = {0.f,0.f}, ee1 = {0.f,0.f};
#pragma unroll
        for (int q = 0; q < 8; ++q) {
            ee0 = fma2(a[q], we0[q], ee0);
            ee1 = fma2(a[q], we1[q], ee1);
        }
        eesum0 += ee0;            // running sum for the analytic self-loop
        eesum1 += ee1;
        float v0 = xls.x + xrv.x + ee0.x + ee0.y;
        float v1 = xls.y + xrv.y + ee1.x + ee1.y;
        v0 = fmaxf(v0, NEG_SLOPE * v0);   // leaky-relu, exact for slope<1
        v1 = fmaxf(v1, NEG_SLOPE * v1);
        float pl = red16(fmaf(v0, att0, v1 * att1));  // head logit, log2 domain
        if (pl - m > THR) { float r_ = exp2f(m - pl); d *= r_; acc0 *= r_; acc1 *= r_; m = pl; }
        float w = exp2f(pl - m);
        d += w;
        acc0 = fmaf(w, xls.x, acc0);
        acc1 = fmaf(w, xls.y, acc1);
    };

    if (degn > 0) {
        // csr entries for real edges row..row+3 (clamped to rlast), kept 4 ahead
        int2 se_a = csr[row];
        int2 se_b = csr[min(row + 1, rlast)];
        int2 se_c = csr[min(row + 2, rlast)];
        int2 se_d = csr[min(row + 3, rlast)];

        const float4* apA = (const float4*)(ea + (size_t)se_a.y * EDGE_DIM);
        float4 Aa0 = apA[0], Aa1 = apA[1], Aa2 = apA[2], Aa3 = apA[3];
        v2f xlA = xl2[(size_t)se_a.x * 64 + lane];
        const float4* apB = (const float4*)(ea + (size_t)se_b.y * EDGE_DIM);
        float4 Ab0 = apB[0], Ab1 = apB[1], Ab2 = apB[2], Ab3 = apB[3];
        v2f xlB = xl2[(size_t)se_b.x * 64 + lane];

        int i = row;
        for (; i + 1 < rend - 1; i += 2) {
            body(Aa0, Aa1, Aa2, Aa3, xlA);
            {   // refill slot A with edge i+2 (csr already resident in se_c)
                xlA = xl2[(size_t)se_c.x * 64 + lane];
                const float4* ap = (const float4*)(ea + (size_t)se_c.y * EDGE_DIM);
                Aa0 = ap[0]; Aa1 = ap[1]; Aa2 = ap[2]; Aa3 = ap[3];
                se_c = csr[min(i + 4, rlast)];
            }
            body(Ab0, Ab1, Ab2, Ab3, xlB);
            {   // refill slot B with edge i+3 (csr already resident in se_d)
                xlB = xl2[(size_t)se_d.x * 64 + lane];
                const float4* ap = (const float4*)(ea + (size_t)se_d.y * EDGE_DIM);
                Ab0 = ap[0]; Ab1 = ap[1]; Ab2 = ap[2]; Ab3 = ap[3];
                se_d = csr[min(i + 5, rlast)];
            }
        }
        if (i < rend - 1) body(Aa0, Aa1, Aa2, Aa3, xlA);   // odd tail
    }

    // ---- analytic self-loop: attr = mean(incoming attrs) -> ee = mean(ee_edges) ----
    {
        float inv = (degn > 0) ? 1.0f / (float)degn : 0.0f;
        v2f ee0 = eesum0 * (v2f){inv, inv};
        v2f ee1 = eesum1 * (v2f){inv, inv};
        v2f xls = xl2[(size_t)node * 64 + lane];
        float v0 = xls.x + xrv.x + ee0.x + ee0.y;
        float v1 = xls.y + xrv.y + ee1.x + ee1.y;
        v0 = fmaxf(v0, NEG_SLOPE * v0);
        v1 = fmaxf(v1, NEG_SLOPE * v1);
        float pl = red16(fmaf(v0, att0, v1 * att1));
        if (pl - m > THR) { float r_ = exp2f(m - pl); d *= r_; acc0 *= r_; acc1 *= r_; m = pl; }
        float w = exp2f(pl - m);
        d += w;
        acc0 = fmaf(w, xls.x, acc0);
        acc1 = fmaf(w, xls.y, acc1);
    }

    float2 bv = ((const float2*)bias)[lane];
    float o0 = acc0 / d + bv.x;
    float o1 = acc1 / d + bv.y;
    if (DO_ELU) {
        o0 = (o0 > 0.0f) ? o0 : (__expf(o0) - 1.0f);
        o1 = (o1 > 0.0f) ? o1 : (__expf(o1) - 1.0f);
    }
    *(float2*)(y + (size_t)node * 128 + c) = make_float2(o0, o1);
}

// ---------------- pool (segmented reduction over sorted batch) + head ----------------
__global__ __launch_bounds__(256) void pool_csr(const float* __restrict__ y,
                                                const int* __restrict__ batch,
                                                float* __restrict__ gsum,
                                                float* __restrict__ gcnt) {
    int base = blockIdx.x * 256;
    int t = threadIdx.x;
    int c = t & 127, h = t >> 7;
    int n = base + h;
    int end = min(base + 256, N_NODES);
    if (n >= end) return;
    float acc = 0.0f, cnt = 0.0f;
    int curb = batch[n];
    for (; n < end; n += 2) {
        int b = batch[n];
        if (b != curb) {
            atomicAdd(&gsum[curb * 128 + c], acc);
            if (c == 0) atomicAdd(&gcnt[curb], cnt);
            acc = 0.0f; cnt = 0.0f; curb = b;
        }
        acc += y[(long long)n * 128 + c];
        cnt += 1.0f;
    }
    atomicAdd(&gsum[curb * 128 + c], acc);
    if (c == 0) atomicAdd(&gcnt[curb], cnt);
}

__global__ __launch_bounds__(128) void head_kernel(
    const float* __restrict__ gsum, const float* __restrict__ gcnt,
    const float* __restrict__ Wg1, const float* __restrict__ bg1,
    const float* __restrict__ Wg2, const float* __restrict__ bg2,
    const float* __restrict__ Wp, const float* __restrict__ bp,
    float* __restrict__ out)
{
    int b = blockIdx.x;
    int j = threadIdx.x;
    __shared__ float g[128], h[128];
    float cntv = fmaxf(gcnt[b], 1.0f);
    g[j] = gsum[b * 128 + j] / cntv;
    __syncthreads();
    float a = bg1[j];
    for (int k = 0; k < 128; ++k) a += g[k] * Wg1[j * 128 + k];
    h[j] = fmaxf(a, 0.0f);
    __syncthreads();
    if (j < 15) {
        float o = bg2[j];
        for (int k = 0; k < 128; ++k) o += h[k] * Wg2[j * 128 + k];
        out[b * 25 + j] = o;
    }
    if (j >= 64 && j < 74) {
        int p = j - 64;
        float o = bp[p];
        for (int k = 0; k < 128; ++k) o += g[k] * Wp[p * 128 + k];
        out[b * 25 + 15 + p] = o;
    }
}

// ---------------- launch ----------------
extern "C" void kernel_launch(void* const* d_in, const int* in_sizes, int n_in,
                              void* d_out, int out_size, void* d_ws, size_t ws_size,
                              hipStream_t stream)
{
    const float* x     = (const float*)d_in[0];
    const int*   ei    = (const int*)  d_in[1];
    const float* ea    = (const float*)d_in[2];
    const int*   batch = (const int*)  d_in[3];
    const float* W1l = (const float*)d_in[4],  *b1l  = (const float*)d_in[5];
    const float* W1r = (const float*)d_in[6],  *b1r  = (const float*)d_in[7];
    const float* W1e = (const float*)d_in[8],  *att1 = (const float*)d_in[9];
    const float* bias1 = (const float*)d_in[10];
    const float* W2l = (const float*)d_in[11], *b2l  = (const float*)d_in[12];
    const float* W2r = (const float*)d_in[13], *b2r  = (const float*)d_in[14];
    const float* W2e = (const float*)d_in[15], *att2 = (const float*)d_in[16];
    const float* bias2 = (const float*)d_in[17];
    const float* Wg1 = (const float*)d_in[18], *bg1 = (const float*)d_in[19];
    const float* Wg2 = (const float*)d_in[20], *bg2 = (const float*)d_in[21];
    const float* Wp  = (const float*)d_in[22], *bp  = (const float*)d_in[23];
    const int* src = ei;
    const int* dst = ei + N_EDGES;

    // workspace layout (float units; all segment starts 8B-aligned)
    float* ws = (float*)d_ws;
    size_t o = 0;
    float* xl    = ws + o; o += (size_t)N_NODES * 128;
    float* xr    = ws + o; o += (size_t)N_NODES * 128;
    float* y     = ws + o; o += (size_t)N_NODES * 128;
    int2* csr    = (int2*)(ws + o); o += (size_t)EN_TOT * 2;
    int* offs    = (int*)(ws + o); o += (size_t)N_NODES + 2;
    int* rank    = (int*)(ws + o); o += (size_t)N_EDGES;
    int* deg     = (int*)(ws + o); o += (size_t)N_NODES;          // start of zero region
    float* gsum  = ws + o; o += (size_t)BATCH * 128;
    float* gcnt  = ws + o; o += (size_t)BATCH;                     // end of zero region
    int* bsum    = (int*)(ws + o); o += 512;
    int* incl    = (int*)y;  // scan temp, dead before y is written

    float* out = (float*)d_out;

    // zero deg, gsum, gcnt (contiguous)
    long long nz = (long long)N_NODES + BATCH * 128 + BATCH;
    zero_kernel<<<512, 256, 0, stream>>>((float*)deg, nz);

    // ---- CSR build (shared by both layers) ----
    count_deg<<<(N_EDGES + 255) / 256, 256, 0, stream>>>(dst, deg, rank);
    scan1<<<NB_SCAN, 256, 0, stream>>>(deg, incl, bsum);
    scan2<<<1, 512, 0, stream>>>(bsum);
    scan3<<<NB_SCAN, 256, 0, stream>>>(incl, deg, bsum, offs);
    scatter<<<(N_EDGES + 255) / 256, 256, 0, stream>>>(src, dst, offs, rank, csr);

    const int GAT_BLK = (N_NODES + 3) / 4;
    const int DL_BLK  = (N_NODES + 31) / 32;

    // ---- layer 1 ----
    dual_linear<32><<<DL_BLK, 256, 0, stream>>>(x, W1l, b1l, W1r, b1r, xl, xr, N_NODES);
    gat_fused<1><<<GAT_BLK, 256, 0, stream>>>(offs, csr, ea,
                                              W1e, att1, (const v2f*)xl, (const v2f*)xr, bias1, y);

    // ---- layer 2 ----
    dual_linear<128><<<DL_BLK, 256, 0, stream>>>(y, W2l, b2l, W2r, b2r, xl, xr, N_NODES);
    gat_fused<0><<<GAT_BLK, 256, 0, stream>>>(offs, csr, ea,
                                              W2e, att2, (const v2f*)xl, (const v2f*)xr, bias2, y);

    // ---- pool + head ----
    pool_csr<<<(N_NODES + 255) / 256, 256, 0, stream>>>(y, batch, gsum, gcnt);
    head_kernel<<<BATCH, 128, 0, stream>>>(gsum, gcnt, Wg1, bg1, Wg2, bg2, Wp, bp, out);
}

// Round 20
// 772.837 us; speedup vs baseline: 1.1133x; 1.0078x over previous
//
#include <hip/hip_runtime.h>
#include <math.h>

#define N_NODES 100000
#define N_EDGES 1600000
#define EN_TOT  (N_EDGES + N_NODES)
#define BATCH   16
#define EDGE_DIM 16
#define NEG_SLOPE 0.2f
#define NB_SCAN 391   // ceil(N_NODES/256)
#define LOG2E 1.44269504f

typedef float v2f __attribute__((ext_vector_type(2)));

__device__ __forceinline__ int rfl(int v) { return __builtin_amdgcn_readfirstlane(v); }

__device__ __forceinline__ v2f fma2(v2f a, v2f b, v2f c) {
#if __has_builtin(__builtin_elementwise_fma)
    return __builtin_elementwise_fma(a, b, c);
#else
    v2f r; r.x = fmaf(a.x, b.x, c.x); r.y = fmaf(a.y, b.y, c.y); return r;
#endif
}

// DPP cross-lane add (VALU pipe, no DS round-trip / lgkmcnt stall).
template<int CTRL>
__device__ __forceinline__ float dpp_add(float p) {
    int t = __builtin_amdgcn_update_dpp(0, __float_as_int(p), CTRL, 0xF, 0xF, true);
    return p + __int_as_float(t);
}
// reduce-add over each 16-lane group, result in ALL 16 lanes.
__device__ __forceinline__ float red16(float p) {
    p = dpp_add<0xB1>(p);    // quad_perm [1,0,3,2] : xor1
    p = dpp_add<0x4E>(p);    // quad_perm [2,3,0,1] : xor2
    p = dpp_add<0x141>(p);   // row_half_mirror     : xor4-equivalent
    p = dpp_add<0x140>(p);   // row_mirror          : xor8-equivalent
    return p;
}

// ---------------- utility ----------------
__global__ void zero_kernel(float* __restrict__ p, long long n) {
    long long i = (long long)blockIdx.x * blockDim.x + threadIdx.x;
    long long stride = (long long)gridDim.x * blockDim.x;
    for (; i < n; i += stride) p[i] = 0.0f;
}

// ---------------- CSR build ----------------
// count_deg also records each edge's within-node rank (the atomic's return value)
// so scatter needs NO atomics at all.
__global__ void count_deg(const int* __restrict__ dst, int* __restrict__ deg,
                          int* __restrict__ rank) {
    int e = blockIdx.x * 256 + threadIdx.x;
    if (e < N_EDGES) rank[e] = atomicAdd(&deg[dst[e]], 1);
}

__global__ __launch_bounds__(256) void scan1(const int* __restrict__ deg,
                                             int* __restrict__ incl, int* __restrict__ bsum) {
    __shared__ int s[256];
    int n = blockIdx.x * 256 + threadIdx.x;
    int v = (n < N_NODES) ? deg[n] + 1 : 0;
    s[threadIdx.x] = v;
    __syncthreads();
    for (int off = 1; off < 256; off <<= 1) {
        int t = (threadIdx.x >= off) ? s[threadIdx.x - off] : 0;
        __syncthreads();
        s[threadIdx.x] += t;
        __syncthreads();
    }
    if (n < N_NODES) incl[n] = s[threadIdx.x];
    if (threadIdx.x == 255) bsum[blockIdx.x] = s[255];
}

__global__ __launch_bounds__(512) void scan2(int* __restrict__ bsum) {
    __shared__ int s[512];
    int t = threadIdx.x;
    int v = (t < NB_SCAN) ? bsum[t] : 0;
    s[t] = v;
    __syncthreads();
    for (int off = 1; off < 512; off <<= 1) {
        int u = (t >= off) ? s[t - off] : 0;
        __syncthreads();
        s[t] += u;
        __syncthreads();
    }
    if (t < NB_SCAN) bsum[t] = s[t] - v;  // exclusive block prefix
}

__global__ void scan3(const int* __restrict__ incl, const int* __restrict__ deg,
                      const int* __restrict__ bsum, int* __restrict__ offs) {
    int n = blockIdx.x * 256 + threadIdx.x;
    if (n < N_NODES) offs[n] = incl[n] - (deg[n] + 1) + bsum[blockIdx.x];
    if (n == 0) offs[N_NODES] = EN_TOT;
}

// scatter real edges into CSR slots (packed {src, eid}) — atomic-free via rank[].
// Row layout: [offs[n], offs[n+1]-1) = real edges; slot offs[n+1]-1 reserved
// (self-loop, handled analytically in gat_fused — never read).
__global__ void scatter(const int* __restrict__ src, const int* __restrict__ dst,
                        const int* __restrict__ offs, const int* __restrict__ rank,
                        int2* __restrict__ csr) {
    int e = blockIdx.x * 256 + threadIdx.x;
    if (e < N_EDGES) {
        csr[offs[dst[e]] + rank[e]] = make_int2(src[e], e);
    }
}

// ---------------- dense transforms ----------------
// R10-proven structure; float4 LDS staging (ds_read_b128 broadcast).
// Scalar float acc[32] + tight kk loop (no ext-vector acc -> no R6 spill).
template<int K>
__global__ __launch_bounds__(256) void dual_linear(
    const float* __restrict__ in,
    const float* __restrict__ Wl, const float* __restrict__ bl,
    const float* __restrict__ Wr, const float* __restrict__ br,
    float* __restrict__ outl, float* __restrict__ outr, int N)
{
    constexpr int ROWS = 32;
    constexpr int K4 = K / 4;
    __shared__ float4 srow[ROWS][K4];
    int t = threadIdx.x;
    int base = blockIdx.x * ROWS;
    {
        const float4* in4 = (const float4*)in;
        for (int i = t; i < ROWS * K4; i += 256) {
            int r = i / K4, k = i - r * K4;
            int n = base + r;
            srow[r][k] = (n < N) ? in4[(size_t)n * K4 + k] : make_float4(0.f, 0.f, 0.f, 0.f);
        }
    }
    __syncthreads();
    const float* W  = (t < 128) ? Wl : Wr;
    const float* bb = (t < 128) ? bl : br;
    float* outp     = (t < 128) ? outl : outr;
    int j = t & 127;
    float bj = bb[j];
    float acc[ROWS];
#pragma unroll
    for (int r = 0; r < ROWS; ++r) acc[r] = bj;
    const float4* W4 = (const float4*)(W + (size_t)j * K);
    for (int kk = 0; kk < K4; ++kk) {
        float4 w = W4[kk];
#pragma unroll
        for (int r = 0; r < ROWS; ++r) {
            float4 a = srow[r][kk];   // wave-uniform -> ds_read_b128 broadcast
            acc[r] = fmaf(a.x, w.x, acc[r]);
            acc[r] = fmaf(a.y, w.y, acc[r]);
            acc[r] = fmaf(a.z, w.z, acc[r]);
            acc[r] = fmaf(a.w, w.w, acc[r]);
        }
    }
    for (int r = 0; r < ROWS; ++r) {
        int n = base + r;
        if (n < N) outp[(long long)n * 128 + j] = acc[r];
    }
}

// ---------------- fused GATv2 ----------------
// R18 structure (scalar body, 256-thr, depth-2 + csr-ahead-4, DPP reduce) with the
// self-loop handled ANALYTICALLY (ee linear in attr -> self-loop ee = mean of real
// edges' ee, accumulated in registers). All pipelined edges are real.
// CRITICAL: attr addresses go through rfl(eid) so the compiler provably keeps the
// attr loads on the SCALAR (s_load -> SGPR) path — R19 lost this (SGPR 64->48) and
// regressed 223->267 us.
template<int DO_ELU>
__global__ __launch_bounds__(256) void gat_fused(
    const int* __restrict__ offs, const int2* __restrict__ csr,
    const float* __restrict__ ea,
    const float* __restrict__ We, const float* __restrict__ att,
    const v2f* __restrict__ xl2, const v2f* __restrict__ xr2,
    const float* __restrict__ bias, float* __restrict__ y)
{
    int node = blockIdx.x * 4 + (threadIdx.x >> 6);
    if (node >= N_NODES) return;
    int lane = threadIdx.x & 63;
    int c = lane << 1;   // channels c, c+1 (same head)

    v2f we0[8], we1[8];
    {
        const v2f* Wa = (const v2f*)(We + (size_t)c * EDGE_DIM);
        const v2f* Wb = (const v2f*)(We + (size_t)(c + 1) * EDGE_DIM);
#pragma unroll
        for (int q = 0; q < 8; ++q) { we0[q] = Wa[q]; we1[q] = Wb[q]; }
    }
    float2 atv = ((const float2*)att)[lane];
    float att0 = atv.x * LOG2E, att1 = atv.y * LOG2E;
    const float THR = 8.0f * LOG2E;

    int row  = rfl(offs[node]);
    int rend = rfl(offs[node + 1]);
    int degn  = rend - 1 - row;   // real edges
    int rlast = rend - 2;         // last real edge index
    v2f xrv = xr2[(size_t)node * 64 + lane];

    float m = -INFINITY, d = 0.f, acc0 = 0.f, acc1 = 0.f;
    v2f eesum0 = {0.f, 0.f}, eesum1 = {0.f, 0.f};

    // wave-uniform attr pointer: rfl forces the scalar-load path
    auto attr4 = [&](int eid) -> const float4* {
        return (const float4*)(ea + (size_t)rfl(eid) * EDGE_DIM);
    };

    // one real edge's full compute; attrs arrive in SGPRs, xls in VGPRs
    auto body = [&](float4 A0, float4 A1, float4 A2, float4 A3, v2f xls) {
        v2f a[8] = { {A0.x,A0.y},{A0.z,A0.w},{A1.x,A1.y},{A1.z,A1.w},
                     {A2.x,A2.y},{A2.z,A2.w},{A3.x,A3.y},{A3.z,A3.w} };
        v2f ee0 = {0.f,0.f}, ee1 = {0.f,0.f};
#pragma unroll
        for (int q = 0; q < 8; ++q) {
            ee0 = fma2(a[q], we0[q], ee0);
            ee1 = fma2(a[q], we1[q], ee1);
        }
        eesum0 += ee0;            // running sum for the analytic self-loop
        eesum1 += ee1;
        float v0 = xls.x + xrv.x + ee0.x + ee0.y;
        float v1 = xls.y + xrv.y + ee1.x + ee1.y;
        v0 = fmaxf(v0, NEG_SLOPE * v0);   // leaky-relu, exact for slope<1
        v1 = fmaxf(v1, NEG_SLOPE * v1);
        float pl = red16(fmaf(v0, att0, v1 * att1));  // head logit, log2 domain
        if (pl - m > THR) { float r_ = exp2f(m - pl); d *= r_; acc0 *= r_; acc1 *= r_; m = pl; }
        float w = exp2f(pl - m);
        d += w;
        acc0 = fmaf(w, xls.x, acc0);
        acc1 = fmaf(w, xls.y, acc1);
    };

    if (degn > 0) {
        // csr entries for real edges row..row+3 (clamped to rlast), kept 4 ahead
        int2 se_a = csr[row];
        int2 se_b = csr[min(row + 1, rlast)];
        int2 se_c = csr[min(row + 2, rlast)];
        int2 se_d = csr[min(row + 3, rlast)];

        const float4* apA = attr4(se_a.y);
        float4 Aa0 = apA[0], Aa1 = apA[1], Aa2 = apA[2], Aa3 = apA[3];
        v2f xlA = xl2[(size_t)se_a.x * 64 + lane];
        const float4* apB = attr4(se_b.y);
        float4 Ab0 = apB[0], Ab1 = apB[1], Ab2 = apB[2], Ab3 = apB[3];
        v2f xlB = xl2[(size_t)se_b.x * 64 + lane];

        int i = row;
        for (; i + 1 < rend - 1; i += 2) {
            body(Aa0, Aa1, Aa2, Aa3, xlA);
            {   // refill slot A with edge i+2 (csr already resident in se_c)
                xlA = xl2[(size_t)se_c.x * 64 + lane];
                const float4* ap = attr4(se_c.y);
                Aa0 = ap[0]; Aa1 = ap[1]; Aa2 = ap[2]; Aa3 = ap[3];
                se_c = csr[min(i + 4, rlast)];
            }
            body(Ab0, Ab1, Ab2, Ab3, xlB);
            {   // refill slot B with edge i+3 (csr already resident in se_d)
                xlB = xl2[(size_t)se_d.x * 64 + lane];
                const float4* ap = attr4(se_d.y);
                Ab0 = ap[0]; Ab1 = ap[1]; Ab2 = ap[2]; Ab3 = ap[3];
                se_d = csr[min(i + 5, rlast)];
            }
        }
        if (i < rend - 1) body(Aa0, Aa1, Aa2, Aa3, xlA);   // odd tail
    }

    // ---- analytic self-loop: attr = mean(incoming attrs) -> ee = mean(ee_edges) ----
    {
        float inv = (degn > 0) ? 1.0f / (float)degn : 0.0f;
        v2f ee0 = eesum0 * (v2f){inv, inv};
        v2f ee1 = eesum1 * (v2f){inv, inv};
        v2f xls = xl2[(size_t)node * 64 + lane];
        float v0 = xls.x + xrv.x + ee0.x + ee0.y;
        float v1 = xls.y + xrv.y + ee1.x + ee1.y;
        v0 = fmaxf(v0, NEG_SLOPE * v0);
        v1 = fmaxf(v1, NEG_SLOPE * v1);
        float pl = red16(fmaf(v0, att0, v1 * att1));
        if (pl - m > THR) { float r_ = exp2f(m - pl); d *= r_; acc0 *= r_; acc1 *= r_; m = pl; }
        float w = exp2f(pl - m);
        d += w;
        acc0 = fmaf(w, xls.x, acc0);
        acc1 = fmaf(w, xls.y, acc1);
    }

    float2 bv = ((const float2*)bias)[lane];
    float o0 = acc0 / d + bv.x;
    float o1 = acc1 / d + bv.y;
    if (DO_ELU) {
        o0 = (o0 > 0.0f) ? o0 : (__expf(o0) - 1.0f);
        o1 = (o1 > 0.0f) ? o1 : (__expf(o1) - 1.0f);
    }
    *(float2*)(y + (size_t)node * 128 + c) = make_float2(o0, o1);
}

// ---------------- pool (segmented reduction over sorted batch) + head ----------------
__global__ __launch_bounds__(256) void pool_csr(const float* __restrict__ y,
                                                const int* __restrict__ batch,
                                                float* __restrict__ gsum,
                                                float* __restrict__ gcnt) {
    int base = blockIdx.x * 256;
    int t = threadIdx.x;
    int c = t & 127, h = t >> 7;
    int n = base + h;
    int end = min(base + 256, N_NODES);
    if (n >= end) return;
    float acc = 0.0f, cnt = 0.0f;
    int curb = batch[n];
    for (; n < end; n += 2) {
        int b = batch[n];
        if (b != curb) {
            atomicAdd(&gsum[curb * 128 + c], acc);
            if (c == 0) atomicAdd(&gcnt[curb], cnt);
            acc = 0.0f; cnt = 0.0f; curb = b;
        }
        acc += y[(long long)n * 128 + c];
        cnt += 1.0f;
    }
    atomicAdd(&gsum[curb * 128 + c], acc);
    if (c == 0) atomicAdd(&gcnt[curb], cnt);
}

__global__ __launch_bounds__(128) void head_kernel(
    const float* __restrict__ gsum, const float* __restrict__ gcnt,
    const float* __restrict__ Wg1, const float* __restrict__ bg1,
    const float* __restrict__ Wg2, const float* __restrict__ bg2,
    const float* __restrict__ Wp, const float* __restrict__ bp,
    float* __restrict__ out)
{
    int b = blockIdx.x;
    int j = threadIdx.x;
    __shared__ float g[128], h[128];
    float cntv = fmaxf(gcnt[b], 1.0f);
    g[j] = gsum[b * 128 + j] / cntv;
    __syncthreads();
    float a = bg1[j];
    for (int k = 0; k < 128; ++k) a += g[k] * Wg1[j * 128 + k];
    h[j] = fmaxf(a, 0.0f);
    __syncthreads();
    if (j < 15) {
        float o = bg2[j];
        for (int k = 0; k < 128; ++k) o += h[k] * Wg2[j * 128 + k];
        out[b * 25 + j] = o;
    }
    if (j >= 64 && j < 74) {
        int p = j - 64;
        float o = bp[p];
        for (int k = 0; k < 128; ++k) o += g[k] * Wp[p * 128 + k];
        out[b * 25 + 15 + p] = o;
    }
}

// ---------------- launch ----------------
extern "C" void kernel_launch(void* const* d_in, const int* in_sizes, int n_in,
                              void* d_out, int out_size, void* d_ws, size_t ws_size,
                              hipStream_t stream)
{
    const float* x     = (const float*)d_in[0];
    const int*   ei    = (const int*)  d_in[1];
    const float* ea    = (const float*)d_in[2];
    const int*   batch = (const int*)  d_in[3];
    const float* W1l = (const float*)d_in[4],  *b1l  = (const float*)d_in[5];
    const float* W1r = (const float*)d_in[6],  *b1r  = (const float*)d_in[7];
    const float* W1e = (const float*)d_in[8],  *att1 = (const float*)d_in[9];
    const float* bias1 = (const float*)d_in[10];
    const float* W2l = (const float*)d_in[11], *b2l  = (const float*)d_in[12];
    const float* W2r = (const float*)d_in[13], *b2r  = (const float*)d_in[14];
    const float* W2e = (const float*)d_in[15], *att2 = (const float*)d_in[16];
    const float* bias2 = (const float*)d_in[17];
    const float* Wg1 = (const float*)d_in[18], *bg1 = (const float*)d_in[19];
    const float* Wg2 = (const float*)d_in[20], *bg2 = (const float*)d_in[21];
    const float* Wp  = (const float*)d_in[22], *bp  = (const float*)d_in[23];
    const int* src = ei;
    const int* dst = ei + N_EDGES;

    // workspace layout (float units; all segment starts 8B-aligned)
    float* ws = (float*)d_ws;
    size_t o = 0;
    float* xl    = ws + o; o += (size_t)N_NODES * 128;
    float* xr    = ws + o; o += (size_t)N_NODES * 128;
    float* y     = ws + o; o += (size_t)N_NODES * 128;
    int2* csr    = (int2*)(ws + o); o += (size_t)EN_TOT * 2;
    int* offs    = (int*)(ws + o); o += (size_t)N_NODES + 2;
    int* rank    = (int*)(ws + o); o += (size_t)N_EDGES;
    int* deg     = (int*)(ws + o); o += (size_t)N_NODES;          // start of zero region
    float* gsum  = ws + o; o += (size_t)BATCH * 128;
    float* gcnt  = ws + o; o += (size_t)BATCH;                     // end of zero region
    int* bsum    = (int*)(ws + o); o += 512;
    int* incl    = (int*)y;  // scan temp, dead before y is written

    float* out = (float*)d_out;

    // zero deg, gsum, gcnt (contiguous)
    long long nz = (long long)N_NODES + BATCH * 128 + BATCH;
    zero_kernel<<<512, 256, 0, stream>>>((float*)deg, nz);

    // ---- CSR build (shared by both layers) ----
    count_deg<<<(N_EDGES + 255) / 256, 256, 0, stream>>>(dst, deg, rank);
    scan1<<<NB_SCAN, 256, 0, stream>>>(deg, incl, bsum);
    scan2<<<1, 512, 0, stream>>>(bsum);
    scan3<<<NB_SCAN, 256, 0, stream>>>(incl, deg, bsum, offs);
    scatter<<<(N_EDGES + 255) / 256, 256, 0, stream>>>(src, dst, offs, rank, csr);

    const int GAT_BLK = (N_NODES + 3) / 4;
    const int DL_BLK  = (N_NODES + 31) / 32;

    // ---- layer 1 ----
    dual_linear<32><<<DL_BLK, 256, 0, stream>>>(x, W1l, b1l, W1r, b1r, xl, xr, N_NODES);
    gat_fused<1><<<GAT_BLK, 256, 0, stream>>>(offs, csr, ea,
                                              W1e, att1, (const v2f*)xl, (const v2f*)xr, bias1, y);

    // ---- layer 2 ----
    dual_linear<128><<<DL_BLK, 256, 0, stream>>>(y, W2l, b2l, W2r, b2r, xl, xr, N_NODES);
    gat_fused<0><<<GAT_BLK, 256, 0, stream>>>(offs, csr, ea,
                                              W2e, att2, (const v2f*)xl, (const v2f*)xr, bias2, y);

    // ---- pool + head ----
    pool_csr<<<(N_NODES + 255) / 256, 256, 0, stream>>>(y, batch, gsum, gcnt);
    head_kernel<<<BATCH, 128, 0, stream>>>(gsum, gcnt, Wg1, bg1, Wg2, bg2, Wp, bp, out);
}